// Round 14
// baseline (280.418 us; speedup 1.0000x reference)
//
#include <hip/hip_runtime.h>
#include <hip/hip_bf16.h>

typedef __hip_bfloat16 bf16;
typedef __attribute__((ext_vector_type(8))) __bf16 bf16x8;
typedef __attribute__((ext_vector_type(8))) short s16x8;
typedef __attribute__((ext_vector_type(4))) float f32x4;
typedef __attribute__((ext_vector_type(16))) float f32x16;

#define AS1 __attribute__((address_space(1)))
#define AS3 __attribute__((address_space(3)))

#define DDIM 2048
#define KDIM 2176   // 2048 (x @ W^T) + 128 (hw @ B_cat) fused K-extension
#define TTOK 16384

// ---------------- K1: merged prep ----------------
// blocks 0-1023: W_base^T -> Wcat[:, :2048]; 1024-2047: A_cat^T -> AcT;
// 2048-3071: B_cat^T -> Wcat[:, 2048:]; 3072-3119: Wr -> WrT[6][2048] fp32

__global__ __launch_bounds__(256) void prep_kernel(
    const float* __restrict__ W, const float* __restrict__ A_s,
    const float* __restrict__ A_r, const float* __restrict__ Bs,
    const float* __restrict__ Br, const float* __restrict__ Wr,
    bf16* __restrict__ Wcat, bf16* __restrict__ AcT, float* __restrict__ WrT) {
  __shared__ bf16 tl[64][65];
  int bid = blockIdx.x, tid = threadIdx.x;
  if (bid < 1024) {
    int bi = bid >> 5, bj = bid & 31;
    int k0 = bi * 64, n0 = bj * 64;
    int r = tid >> 2, c0 = (tid & 3) << 4;
#pragma unroll
    for (int q = 0; q < 4; ++q) {
      f32x4 v = *(const f32x4*)(W + (long)(k0 + r) * DDIM + n0 + c0 + q * 4);
#pragma unroll
      for (int j = 0; j < 4; ++j) tl[r][c0 + q * 4 + j] = __float2bfloat16(v[j]);
    }
    __syncthreads();
    __align__(16) bf16 o[16];
#pragma unroll
    for (int i = 0; i < 16; ++i) o[i] = tl[c0 + i][r];
    *(s16x8*)(Wcat + (long)(n0 + r) * KDIM + k0 + c0) = *(const s16x8*)o;
    *(s16x8*)(Wcat + (long)(n0 + r) * KDIM + k0 + c0 + 8) = *(const s16x8*)(o + 8);
  } else if (bid < 2048) {
    int idx = (bid - 1024) * 256 + tid;            // over 128*2048
    int c = idx >> 11, d = idx & 2047;
    float v = 0.f;
    if (c < 16)       v = A_s[d * 16 + c];
    else if (c < 112) { int cr = c - 16; v = A_r[((long)(cr >> 4) * DDIM + d) * 16 + (cr & 15)]; }
    AcT[(long)c * DDIM + d] = __float2bfloat16(v);
  } else if (bid < 3072) {
    int idx = (bid - 2048) * 256 + tid;            // over 2048*128
    int n = idx >> 7, c = idx & 127;
    float v = 0.f;
    if (c < 16)       v = Bs[c * DDIM + n];
    else if (c < 112) v = Br[(long)(c - 16) * DDIM + n];
    Wcat[(long)n * KDIM + 2048 + c] = __float2bfloat16(v);
  } else {
    int idx = (bid - 3072) * 256 + tid;            // over 6*2048
    int e = idx >> 11, d = idx & 2047;
    WrT[e * 2048 + d] = Wr[d * 6 + e];
  }
}

// ---------------- K0: fp32->bf16 convert of x + fp32 router (coalesced WrT reads) ----------------
// NOTE: gate reduction order must stay bit-identical (top-2 tie flips cost ~0.1 absmax).

__global__ __launch_bounds__(256) void conv_router_kernel(
    const float* __restrict__ x, const float* __restrict__ WrT, const float* __restrict__ br,
    bf16* __restrict__ xh, float* __restrict__ gates) {
  int t = blockIdx.x;
  int tid = threadIdx.x;
  int d0 = tid * 8;
  f32x4 v0 = *(const f32x4*)(x + (long)t * DDIM + d0);
  f32x4 v1 = *(const f32x4*)(x + (long)t * DDIM + d0 + 4);
  __align__(16) bf16 tmp[8];
#pragma unroll
  for (int j = 0; j < 4; ++j) {
    tmp[j] = __float2bfloat16(v0[j]);
    tmp[4 + j] = __float2bfloat16(v1[j]);
  }
  *(s16x8*)(xh + (long)t * KDIM + d0) = *(const s16x8*)tmp;

  float p[6];
#pragma unroll
  for (int e = 0; e < 6; ++e) {
    f32x4 wa = *(const f32x4*)(WrT + e * 2048 + d0);
    f32x4 wb = *(const f32x4*)(WrT + e * 2048 + d0 + 4);
    float s = 0.f;
#pragma unroll
    for (int j = 0; j < 4; ++j) s += v0[j] * wa[j];
#pragma unroll
    for (int j = 0; j < 4; ++j) s += v1[j] * wb[j];
    p[e] = s;
  }
#pragma unroll
  for (int off = 32; off > 0; off >>= 1)
#pragma unroll
    for (int e = 0; e < 6; ++e) p[e] += __shfl_down(p[e], off);
  __shared__ float red[4][6];
  int wave = tid >> 6, lane = tid & 63;
  if (lane == 0)
#pragma unroll
    for (int e = 0; e < 6; ++e) red[wave][e] = p[e];
  __syncthreads();
  if (tid == 0) {
    float g[6], mx = -1e30f;
#pragma unroll
    for (int e = 0; e < 6; ++e) {
      g[e] = red[0][e] + red[1][e] + red[2][e] + red[3][e] + br[e];
      mx = fmaxf(mx, g[e]);
    }
    float s = 0.f;
#pragma unroll
    for (int e = 0; e < 6; ++e) { g[e] = __expf(g[e] - mx); s += g[e]; }
    float inv = 1.f / s;
#pragma unroll
    for (int e = 0; e < 6; ++e) g[e] *= inv;
    int i1 = 0; float w1 = g[0];
#pragma unroll
    for (int e = 1; e < 6; ++e) if (g[e] > w1) { w1 = g[e]; i1 = e; }
    int i2 = -1; float w2 = -1.f;
#pragma unroll
    for (int e = 0; e < 6; ++e) if (e != i1 && g[e] > w2) { w2 = g[e]; i2 = e; }
#pragma unroll
    for (int e = 0; e < 6; ++e)
      gates[(long)t * 6 + e] = (e == i1) ? w1 : (e == i2) ? w2 : 0.f;
  }
}

// ---------------- staging: [ROWS x 64] bf16 tile, LDS-linear (lora kernel) ----------------

template <int ROWS>
__device__ __forceinline__ void stage_tile(const bf16* __restrict__ g, long rs,
                                           bf16* lds, int wave, int lane) {
#pragma unroll
  for (int i = 0; i < (ROWS >> 5); ++i) {
    int chunk_base = (i * 4 + wave) * 64;
    int byte = (chunk_base + lane) * 16;
    int row = byte >> 7;
    int col = (byte & 127) >> 1;
    __builtin_amdgcn_global_load_lds(
        (const AS1 void*)(g + (long)row * rs + col),
        (AS3 void*)(lds + chunk_base * 8), 16, 0, 0);
  }
}

// ---------------- K2: lora, double-buffered; epilogue via LDS repack (coalesced) ----------------

__global__ __launch_bounds__(256) void lora_kernel(
    bf16* __restrict__ xh, const bf16* __restrict__ AcT,
    const float* __restrict__ gates) {
  __shared__ __align__(16) short smem[2 * 192 * 64];   // 48 KB
  __shared__ float G[64][6];
  int tid = threadIdx.x, wave = tid >> 6, lane = tid & 63;
  long m0 = (long)blockIdx.x * 64;

  auto Xbuf = [&](int b) { return (bf16*)smem + b * 192 * 64; };
  auto Bbuf = [&](int b) { return (bf16*)smem + b * 192 * 64 + 64 * 64; };

  stage_tile<64>(xh + m0 * KDIM, KDIM, Xbuf(0), wave, lane);
  stage_tile<128>(AcT, DDIM, Bbuf(0), wave, lane);
  for (int i = tid; i < 384; i += 256) G[i / 6][i % 6] = gates[(m0 + i / 6) * 6 + i % 6];
  __syncthreads();

  f32x4 acc[7];
#pragma unroll
  for (int i = 0; i < 7; ++i) acc[i] = f32x4{0.f, 0.f, 0.f, 0.f};

  for (int kt = 0; kt < 32; ++kt) {
    int cur = kt & 1;
    if (kt < 31) {
      int k1 = (kt + 1) * 64;
      stage_tile<64>(xh + m0 * KDIM + k1, KDIM, Xbuf(cur ^ 1), wave, lane);
      stage_tile<128>(AcT + k1, DDIM, Bbuf(cur ^ 1), wave, lane);
    }
    if (kt > 0) {
      if (kt < 31) asm volatile("s_waitcnt vmcnt(6)" ::: "memory");
      else         asm volatile("s_waitcnt vmcnt(0)" ::: "memory");
      __builtin_amdgcn_sched_barrier(0);
      __builtin_amdgcn_s_barrier();
      __builtin_amdgcn_sched_barrier(0);
    }
    bf16* X_s = Xbuf(cur);
    bf16* B_s = Bbuf(cur);
#pragma unroll
    for (int kk = 0; kk < 2; ++kk) {
      bf16x8 a = *(const bf16x8*)(X_s + (16 * wave + (lane & 15)) * 64 + kk * 32 + (lane >> 4) * 8);
#pragma unroll
      for (int nr = 0; nr < 7; ++nr) {
        bf16x8 b = *(const bf16x8*)(B_s + (16 * nr + (lane & 15)) * 64 + kk * 32 + (lane >> 4) * 8);
        acc[nr] = __builtin_amdgcn_mfma_f32_16x16x32_bf16(a, b, acc[nr], 0, 0, 0);
      }
    }
    __builtin_amdgcn_sched_barrier(0);
    __builtin_amdgcn_s_barrier();
  }

  // epilogue: gate-scale into LDS [64][128], then coalesced 16B global stores
  bf16* H = (bf16*)smem;
#pragma unroll
  for (int nr = 0; nr < 7; ++nr) {
    int c = nr * 16 + (lane & 15);
#pragma unroll
    for (int reg = 0; reg < 4; ++reg) {
      int tl = 16 * wave + 4 * (lane >> 4) + reg;
      float wgt = (c < 16) ? 1.f : G[tl][(c - 16) >> 4];
      H[tl * 128 + c] = __float2bfloat16(acc[nr][reg] * wgt);
    }
  }
  {
    int c = 112 + (lane & 15);
#pragma unroll
    for (int reg = 0; reg < 4; ++reg) {
      int tl = 16 * wave + 4 * (lane >> 4) + reg;
      H[tl * 128 + c] = __float2bfloat16(0.f);
    }
  }
  __syncthreads();
#pragma unroll
  for (int p = 0; p < 4; ++p) {
    int v = p * 256 + tid;
    int row = v >> 4, ch = (v & 15) * 8;
    *(s16x8*)(xh + (m0 + row) * KDIM + 2048 + ch) = *(const s16x8*)(H + row * 128 + ch);
  }
}

// ---------------- kernel B v10: v6/v13 skeleton with 32x32x16 MFMA ----------------
// Same LDS layout/stage schedule/vmcnt(6)@q1,q3/barriers. Changes: frag reads use the
// rounds-4/5-proven 32x32 lane mapping (row=lane&31, k-half=(lane>>5)*8) with the same
// row-XOR swizzle; 8 MFMA/phase; direct 128B-coalesced epilogue (m74/m101 C/D mapping).

__global__ __launch_bounds__(512, 2) void gemm256_kernel(
    const bf16* __restrict__ xh, const bf16* __restrict__ Wcat,
    const float* __restrict__ b_base, float* __restrict__ out) {
  extern __shared__ char sm[];
  int tid = threadIdx.x, wave = tid >> 6, lane = tid & 63;
  int wr = wave >> 2, wc = wave & 3;   // 2x4 wave grid; per-wave 128 x 64 output

  // XCD-bijective swizzle (nwg = 512, divisible by 8)
  int bid = blockIdx.x;
  int cpx = gridDim.x >> 3;
  int swz = (bid & 7) * cpx + (bid >> 3);
  long m0 = (long)(swz >> 3) * 256;    // 64 x 8 grid
  int n0 = (swz & 7) * 256;

  float bias[2];
#pragma unroll
  for (int nf = 0; nf < 2; ++nf) bias[nf] = b_base[n0 + wc * 64 + nf * 32 + (lane & 31)];

  f32x16 acc[4][2];
#pragma unroll
  for (int i = 0; i < 4; ++i)
#pragma unroll
    for (int j = 0; j < 2; ++j)
#pragma unroll
      for (int r = 0; r < 16; ++r) acc[i][j][r] = 0.f;

  const bf16* Agl = xh + m0 * KDIM;
  const bf16* Bgl = Wcat + (long)n0 * KDIM;

  // stage one 8KB subtile (op: 0=A,1=B; half h; col-half s) of K-tile t: 1 load/thread
  auto stage_sub = [&](int t, int op, int h, int s) {
    int row = tid >> 2;
    int scol = ((((tid & 3) << 4) ^ (((row >> 1) & 3) << 4)) >> 1);
    const bf16* src = (op ? Bgl : Agl) + (long)(h * 128 + row) * KDIM + t * 64 + s * 32 + scol;
    char* dst = sm + (t & 1) * 65536 + op * 32768 + (h * 2 + s) * 8192 + tid * 16;
    __builtin_amdgcn_global_load_lds((const AS1 void*)src, (AS3 void*)dst, 16, 0, 0);
  };

  bf16x8 a[2][2], b[2][2];   // [ks][frag]

  // phase (s, mh): read frags, optional stage of 2 subtiles, barrier, 8 MFMA, counted vmcnt
  auto phase = [&](int buf, int s, int mh, bool doStage, int stT, int stOp, int stKs, int vm) {
    if (mh == 0) {
      char* Bb = sm + buf * 65536 + 32768 + ((wc >> 1) * 2 + s) * 8192;
#pragma unroll
      for (int nf = 0; nf < 2; ++nf) {
        int r = (wc & 1) * 64 + nf * 32 + (lane & 31);
#pragma unroll
        for (int ks = 0; ks < 2; ++ks)
          b[ks][nf] = *(const bf16x8*)(Bb + r * 64 +
                        ((ks * 32 + ((lane >> 5) << 4)) ^ (((r >> 1) & 3) << 4)));
      }
    }
    char* Ab = sm + buf * 65536 + (wr * 2 + s) * 8192;
#pragma unroll
    for (int mfl = 0; mfl < 2; ++mfl) {
      int r = (mh * 2 + mfl) * 32 + (lane & 31);
#pragma unroll
      for (int ks = 0; ks < 2; ++ks)
        a[ks][mfl] = *(const bf16x8*)(Ab + r * 64 +
                      ((ks * 32 + ((lane >> 5) << 4)) ^ (((r >> 1) & 3) << 4)));
    }
    if (doStage) { stage_sub(stT, stOp, 0, stKs); stage_sub(stT, stOp, 1, stKs); }
    __builtin_amdgcn_s_barrier();
    __builtin_amdgcn_s_setprio(1);
#pragma unroll
    for (int ks = 0; ks < 2; ++ks)
#pragma unroll
      for (int mfl = 0; mfl < 2; ++mfl)
#pragma unroll
        for (int nf = 0; nf < 2; ++nf)
          acc[mh * 2 + mfl][nf] = __builtin_amdgcn_mfma_f32_32x32x16_bf16(
              a[ks][mfl], b[ks][nf], acc[mh * 2 + mfl][nf], 0, 0, 0);
    __builtin_amdgcn_s_setprio(0);
    if (vm == 6)      asm volatile("s_waitcnt vmcnt(6)" ::: "memory");
    else if (vm == 4) asm volatile("s_waitcnt vmcnt(4)" ::: "memory");
    else if (vm == 0) asm volatile("s_waitcnt vmcnt(0)" ::: "memory");
    __builtin_amdgcn_s_barrier();
  };

  // prologue: stage t0 s0+s1, t1 s0 (12 loads/thread); t0s0 resident after vmcnt(8)+barrier
  stage_sub(0, 0, 0, 0); stage_sub(0, 0, 1, 0); stage_sub(0, 1, 0, 0); stage_sub(0, 1, 1, 0);
  stage_sub(0, 0, 0, 1); stage_sub(0, 0, 1, 1); stage_sub(0, 1, 0, 1); stage_sub(0, 1, 1, 1);
  stage_sub(1, 0, 0, 0); stage_sub(1, 0, 1, 0); stage_sub(1, 1, 0, 0); stage_sub(1, 1, 1, 0);
  asm volatile("s_waitcnt vmcnt(8)" ::: "memory");
  __builtin_amdgcn_s_barrier();

  // main loop: K-tiles 0..31; vmcnt only at q1 and q3
  for (int i = 0; i < 16; ++i) {
    int t0 = 2 * i;
    phase(0, 0, 0, true, t0 + 1, 0, 1, -1);
    phase(0, 0, 1, true, t0 + 1, 1, 1, 6);
    phase(0, 1, 0, true, t0 + 2, 0, 0, -1);
    phase(0, 1, 1, true, t0 + 2, 1, 0, 6);
    phase(1, 0, 0, true, t0 + 2, 0, 1, -1);
    phase(1, 0, 1, true, t0 + 2, 1, 1, 6);
    phase(1, 1, 0, true, t0 + 3, 0, 0, -1);
    phase(1, 1, 1, true, t0 + 3, 1, 0, 6);
  }
  // tail: tile 32 stages 33-s1 at q0/q1; vm: q1=6, q3=0 (drain); tile 33 no waits
  phase(0, 0, 0, true, 33, 0, 1, -1);
  phase(0, 0, 1, true, 33, 1, 1, 6);
  phase(0, 1, 0, false, 0, 0, 0, -1);
  phase(0, 1, 1, false, 0, 0, 0, 0);
  phase(1, 0, 0, false, 0, 0, 0, -1);
  phase(1, 0, 1, false, 0, 0, 0, -1);
  phase(1, 1, 0, false, 0, 0, 0, -1);
  phase(1, 1, 1, false, 0, 0, 0, -1);

  // epilogue: direct fp32 stores (128B contiguous per half-wave), bias add
  // C/D mapping (m74/m101): col=lane&31, row=(reg&3)+8*(reg>>2)+4*(lane>>5)
#pragma unroll
  for (int mf = 0; mf < 4; ++mf)
#pragma unroll
    for (int nf = 0; nf < 2; ++nf) {
      long gc = n0 + wc * 64 + nf * 32 + (lane & 31);
#pragma unroll
      for (int reg = 0; reg < 16; ++reg) {
        int row = (reg & 3) + 8 * (reg >> 2) + 4 * (lane >> 5);
        long gr = m0 + wr * 128 + mf * 32 + row;
        out[gr * DDIM + gc] = acc[mf][nf][reg] + bias[nf];
      }
    }
}

// ---------------- launcher ----------------

extern "C" void kernel_launch(void* const* d_in, const int* in_sizes, int n_in,
                              void* d_out, int out_size, void* d_ws, size_t ws_size,
                              hipStream_t stream) {
  const float* x        = (const float*)d_in[0];
  const float* W_base   = (const float*)d_in[1];
  const float* b_base   = (const float*)d_in[2];
  const float* A_s      = (const float*)d_in[3];
  const float* B_s      = (const float*)d_in[4];
  const float* A_r      = (const float*)d_in[5];
  const float* B_r      = (const float*)d_in[6];
  const float* W_router = (const float*)d_in[7];
  const float* b_router = (const float*)d_in[8];
  float* out = (float*)d_out;

  char* ws = (char*)d_ws;
  bf16*  xh    = (bf16*)(ws);                    // 16384*2176*2 = 71,303,168 B
  bf16*  Wcat  = (bf16*)(ws + 71303168);         //  2048*2176*2 =  8,912,896 B
  bf16*  AcT   = (bf16*)(ws + 80216064);         //   128*2048*2 =    524,288 B
  float* gates = (float*)(ws + 80740352);        //   16384*6*4  =    393,216 B
  float* WrT   = (float*)(ws + 81133568);        //    6*2048*4  =     49,152 B

  (void)hipFuncSetAttribute((const void*)gemm256_kernel,
                            hipFuncAttributeMaxDynamicSharedMemorySize, 131072);

  prep_kernel<<<3120, 256, 0, stream>>>(W_base, A_s, A_r, B_s, B_r, W_router, Wcat, AcT, WrT);
  conv_router_kernel<<<TTOK, 256, 0, stream>>>(x, WrT, b_router, xh, gates);
  lora_kernel<<<256, 256, 0, stream>>>(xh, AcT, gates);
  gemm256_kernel<<<512, 512, 131072, stream>>>(xh, Wcat, b_base, out);
}

// Round 15
// 228.674 us; speedup vs baseline: 1.2263x; 1.2263x over previous
//
#include <hip/hip_runtime.h>
#include <hip/hip_bf16.h>

typedef __hip_bfloat16 bf16;
typedef __attribute__((ext_vector_type(8))) __bf16 bf16x8;
typedef __attribute__((ext_vector_type(8))) short s16x8;
typedef __attribute__((ext_vector_type(4))) float f32x4;

#define AS1 __attribute__((address_space(1)))
#define AS3 __attribute__((address_space(3)))

#define DDIM 2048
#define KDIM 2176   // 2048 (x @ W^T) + 128 (hw @ B_cat) fused K-extension
#define TTOK 16384

// ---------------- K1: merged prep ----------------
// blocks 0-1023: W_base^T -> Wcat[:, :2048]; 1024-2047: A_cat^T -> AcT;
// 2048-3071: B_cat^T -> Wcat[:, 2048:]; 3072-3119: Wr -> WrT[6][2048] fp32

__global__ __launch_bounds__(256) void prep_kernel(
    const float* __restrict__ W, const float* __restrict__ A_s,
    const float* __restrict__ A_r, const float* __restrict__ Bs,
    const float* __restrict__ Br, const float* __restrict__ Wr,
    bf16* __restrict__ Wcat, bf16* __restrict__ AcT, float* __restrict__ WrT) {
  __shared__ bf16 tl[64][65];
  int bid = blockIdx.x, tid = threadIdx.x;
  if (bid < 1024) {
    int bi = bid >> 5, bj = bid & 31;
    int k0 = bi * 64, n0 = bj * 64;
    int r = tid >> 2, c0 = (tid & 3) << 4;
#pragma unroll
    for (int q = 0; q < 4; ++q) {
      f32x4 v = *(const f32x4*)(W + (long)(k0 + r) * DDIM + n0 + c0 + q * 4);
#pragma unroll
      for (int j = 0; j < 4; ++j) tl[r][c0 + q * 4 + j] = __float2bfloat16(v[j]);
    }
    __syncthreads();
    __align__(16) bf16 o[16];
#pragma unroll
    for (int i = 0; i < 16; ++i) o[i] = tl[c0 + i][r];
    *(s16x8*)(Wcat + (long)(n0 + r) * KDIM + k0 + c0) = *(const s16x8*)o;
    *(s16x8*)(Wcat + (long)(n0 + r) * KDIM + k0 + c0 + 8) = *(const s16x8*)(o + 8);
  } else if (bid < 2048) {
    int idx = (bid - 1024) * 256 + tid;            // over 128*2048
    int c = idx >> 11, d = idx & 2047;
    float v = 0.f;
    if (c < 16)       v = A_s[d * 16 + c];
    else if (c < 112) { int cr = c - 16; v = A_r[((long)(cr >> 4) * DDIM + d) * 16 + (cr & 15)]; }
    AcT[(long)c * DDIM + d] = __float2bfloat16(v);
  } else if (bid < 3072) {
    int idx = (bid - 2048) * 256 + tid;            // over 2048*128
    int n = idx >> 7, c = idx & 127;
    float v = 0.f;
    if (c < 16)       v = Bs[c * DDIM + n];
    else if (c < 112) v = Br[(long)(c - 16) * DDIM + n];
    Wcat[(long)n * KDIM + 2048 + c] = __float2bfloat16(v);
  } else {
    int idx = (bid - 3072) * 256 + tid;            // over 6*2048
    int e = idx >> 11, d = idx & 2047;
    WrT[e * 2048 + d] = Wr[d * 6 + e];
  }
}

// ---------------- K0: fp32->bf16 convert + fp32 router, 4 tokens/block ----------------
// WrT loaded into registers ONCE per block, reused for 4 tokens (L2 traffic /4).
// Per-token accumulation order, shuffle tree, and cross-wave sum are byte-identical
// to the proven single-token version -> gates bit-identical (no top-2 flip risk).

__global__ __launch_bounds__(256) void conv_router_kernel(
    const float* __restrict__ x, const float* __restrict__ WrT, const float* __restrict__ br,
    bf16* __restrict__ xh, float* __restrict__ gates) {
  int tid = threadIdx.x;
  int d0 = tid * 8;
  long t0 = (long)blockIdx.x * 4;

  f32x4 wa[6], wb[6];
#pragma unroll
  for (int e = 0; e < 6; ++e) {
    wa[e] = *(const f32x4*)(WrT + e * 2048 + d0);
    wb[e] = *(const f32x4*)(WrT + e * 2048 + d0 + 4);
  }

  float p[4][6];
#pragma unroll
  for (int s = 0; s < 4; ++s) {
    long t = t0 + s;
    f32x4 v0 = *(const f32x4*)(x + t * DDIM + d0);
    f32x4 v1 = *(const f32x4*)(x + t * DDIM + d0 + 4);
    __align__(16) bf16 tmp[8];
#pragma unroll
    for (int j = 0; j < 4; ++j) {
      tmp[j] = __float2bfloat16(v0[j]);
      tmp[4 + j] = __float2bfloat16(v1[j]);
    }
    *(s16x8*)(xh + t * KDIM + d0) = *(const s16x8*)tmp;
#pragma unroll
    for (int e = 0; e < 6; ++e) {
      float sum = 0.f;
#pragma unroll
      for (int j = 0; j < 4; ++j) sum += v0[j] * wa[e][j];
#pragma unroll
      for (int j = 0; j < 4; ++j) sum += v1[j] * wb[e][j];
      p[s][e] = sum;
    }
  }

#pragma unroll
  for (int off = 32; off > 0; off >>= 1)
#pragma unroll
    for (int s = 0; s < 4; ++s)
#pragma unroll
      for (int e = 0; e < 6; ++e) p[s][e] += __shfl_down(p[s][e], off);

  __shared__ float red[4][4][6];
  int wave = tid >> 6, lane = tid & 63;
  if (lane == 0)
#pragma unroll
    for (int s = 0; s < 4; ++s)
#pragma unroll
      for (int e = 0; e < 6; ++e) red[s][wave][e] = p[s][e];
  __syncthreads();
  if (tid < 4) {
    int s = tid;
    float g[6], mx = -1e30f;
#pragma unroll
    for (int e = 0; e < 6; ++e) {
      g[e] = red[s][0][e] + red[s][1][e] + red[s][2][e] + red[s][3][e] + br[e];
      mx = fmaxf(mx, g[e]);
    }
    float sm = 0.f;
#pragma unroll
    for (int e = 0; e < 6; ++e) { g[e] = __expf(g[e] - mx); sm += g[e]; }
    float inv = 1.f / sm;
#pragma unroll
    for (int e = 0; e < 6; ++e) g[e] *= inv;
    int i1 = 0; float w1 = g[0];
#pragma unroll
    for (int e = 1; e < 6; ++e) if (g[e] > w1) { w1 = g[e]; i1 = e; }
    int i2 = -1; float w2 = -1.f;
#pragma unroll
    for (int e = 0; e < 6; ++e) if (e != i1 && g[e] > w2) { w2 = g[e]; i2 = e; }
#pragma unroll
    for (int e = 0; e < 6; ++e)
      gates[(t0 + s) * 6 + e] = (e == i1) ? w1 : (e == i2) ? w2 : 0.f;
  }
}

// ---------------- staging: [ROWS x 64] bf16 tile, LDS-linear (lora kernel) ----------------

template <int ROWS>
__device__ __forceinline__ void stage_tile(const bf16* __restrict__ g, long rs,
                                           bf16* lds, int wave, int lane) {
#pragma unroll
  for (int i = 0; i < (ROWS >> 5); ++i) {
    int chunk_base = (i * 4 + wave) * 64;
    int byte = (chunk_base + lane) * 16;
    int row = byte >> 7;
    int col = (byte & 127) >> 1;
    __builtin_amdgcn_global_load_lds(
        (const AS1 void*)(g + (long)row * rs + col),
        (AS3 void*)(lds + chunk_base * 8), 16, 0, 0);
  }
}

// ---------------- K2: lora, double-buffered; epilogue via LDS repack (coalesced) ----------------

__global__ __launch_bounds__(256) void lora_kernel(
    bf16* __restrict__ xh, const bf16* __restrict__ AcT,
    const float* __restrict__ gates) {
  __shared__ __align__(16) short smem[2 * 192 * 64];   // 48 KB
  __shared__ float G[64][6];
  int tid = threadIdx.x, wave = tid >> 6, lane = tid & 63;
  long m0 = (long)blockIdx.x * 64;

  auto Xbuf = [&](int b) { return (bf16*)smem + b * 192 * 64; };
  auto Bbuf = [&](int b) { return (bf16*)smem + b * 192 * 64 + 64 * 64; };

  stage_tile<64>(xh + m0 * KDIM, KDIM, Xbuf(0), wave, lane);
  stage_tile<128>(AcT, DDIM, Bbuf(0), wave, lane);
  for (int i = tid; i < 384; i += 256) G[i / 6][i % 6] = gates[(m0 + i / 6) * 6 + i % 6];
  __syncthreads();

  f32x4 acc[7];
#pragma unroll
  for (int i = 0; i < 7; ++i) acc[i] = f32x4{0.f, 0.f, 0.f, 0.f};

  for (int kt = 0; kt < 32; ++kt) {
    int cur = kt & 1;
    if (kt < 31) {
      int k1 = (kt + 1) * 64;
      stage_tile<64>(xh + m0 * KDIM + k1, KDIM, Xbuf(cur ^ 1), wave, lane);
      stage_tile<128>(AcT + k1, DDIM, Bbuf(cur ^ 1), wave, lane);
    }
    if (kt > 0) {
      if (kt < 31) asm volatile("s_waitcnt vmcnt(6)" ::: "memory");
      else         asm volatile("s_waitcnt vmcnt(0)" ::: "memory");
      __builtin_amdgcn_sched_barrier(0);
      __builtin_amdgcn_s_barrier();
      __builtin_amdgcn_sched_barrier(0);
    }
    bf16* X_s = Xbuf(cur);
    bf16* B_s = Bbuf(cur);
#pragma unroll
    for (int kk = 0; kk < 2; ++kk) {
      bf16x8 a = *(const bf16x8*)(X_s + (16 * wave + (lane & 15)) * 64 + kk * 32 + (lane >> 4) * 8);
#pragma unroll
      for (int nr = 0; nr < 7; ++nr) {
        bf16x8 b = *(const bf16x8*)(B_s + (16 * nr + (lane & 15)) * 64 + kk * 32 + (lane >> 4) * 8);
        acc[nr] = __builtin_amdgcn_mfma_f32_16x16x32_bf16(a, b, acc[nr], 0, 0, 0);
      }
    }
    __builtin_amdgcn_sched_barrier(0);
    __builtin_amdgcn_s_barrier();
  }

  // epilogue: gate-scale into LDS [64][128], then coalesced 16B global stores
  bf16* H = (bf16*)smem;
#pragma unroll
  for (int nr = 0; nr < 7; ++nr) {
    int c = nr * 16 + (lane & 15);
#pragma unroll
    for (int reg = 0; reg < 4; ++reg) {
      int tl = 16 * wave + 4 * (lane >> 4) + reg;
      float wgt = (c < 16) ? 1.f : G[tl][(c - 16) >> 4];
      H[tl * 128 + c] = __float2bfloat16(acc[nr][reg] * wgt);
    }
  }
  {
    int c = 112 + (lane & 15);
#pragma unroll
    for (int reg = 0; reg < 4; ++reg) {
      int tl = 16 * wave + 4 * (lane >> 4) + reg;
      H[tl * 128 + c] = __float2bfloat16(0.f);
    }
  }
  __syncthreads();
#pragma unroll
  for (int p = 0; p < 4; ++p) {
    int v = p * 256 + tid;
    int row = v >> 4, ch = (v & 15) * 8;
    *(s16x8*)(xh + (m0 + row) * KDIM + 2048 + ch) = *(const s16x8*)(H + row * 128 + ch);
  }
}

// ---------------- kernel B (round-13 proven, frozen): 8-phase 256x256, 16x16x32 ----------------
// 96.5% of the 16x16x32 shape's MFMA issue ceiling (141 us floor @ 4.85 cyc/MFMA/CU).

__global__ __launch_bounds__(512, 2) void gemm256_kernel(
    const bf16* __restrict__ xh, const bf16* __restrict__ Wcat,
    const float* __restrict__ b_base, float* __restrict__ out) {
  extern __shared__ char sm[];
  int tid = threadIdx.x, wave = tid >> 6, lane = tid & 63;
  int wr = wave >> 2, wc = wave & 3;   // 2x4 wave grid; per-wave 128 x 64 output

  // XCD-bijective swizzle (nwg = 512, divisible by 8)
  int bid = blockIdx.x;
  int cpx = gridDim.x >> 3;
  int swz = (bid & 7) * cpx + (bid >> 3);
  long m0 = (long)(swz >> 3) * 256;    // 64 x 8 grid
  int n0 = (swz & 7) * 256;

  // proven-0-conflict frag constants: row = lane&15, slot = lane>>4, XOR ((lane>>1)&3)<<4
  int cp = ((lane >> 4) << 4) ^ (((lane >> 1) & 3) << 4);

  float bias[4];
#pragma unroll
  for (int nf = 0; nf < 4; ++nf) bias[nf] = b_base[n0 + wc * 64 + nf * 16 + (lane & 15)];

  f32x4 acc[8][4];
#pragma unroll
  for (int i = 0; i < 8; ++i)
#pragma unroll
    for (int j = 0; j < 4; ++j) acc[i][j] = f32x4{0.f, 0.f, 0.f, 0.f};

  const bf16* Agl = xh + m0 * KDIM;
  const bf16* Bgl = Wcat + (long)n0 * KDIM;

  // stage one 8KB subtile (op: 0=A,1=B; half h; ks s) of K-tile t: 1 load/thread
  auto stage_sub = [&](int t, int op, int h, int s) {
    int row = tid >> 2;
    int scol = ((((tid & 3) << 4) ^ (((row >> 1) & 3) << 4)) >> 1);
    const bf16* src = (op ? Bgl : Agl) + (long)(h * 128 + row) * KDIM + t * 64 + s * 32 + scol;
    char* dst = sm + (t & 1) * 65536 + op * 32768 + (h * 2 + s) * 8192 + tid * 16;
    __builtin_amdgcn_global_load_lds((const AS1 void*)src, (AS3 void*)dst, 16, 0, 0);
  };

  bf16x8 a[4], b[4];

  // phase: quadrant (ks, mh); optional stage of 2 subtiles; counted vmcnt.
  auto phase = [&](int buf, int ks, int mh, bool doStage, int stT, int stOp, int stKs, int vm) {
    if (mh == 0) {
      char* Bb = sm + buf * 65536 + 32768 + ((wc >> 1) * 2 + ks) * 8192;
#pragma unroll
      for (int n = 0; n < 4; ++n)
        b[n] = *(const bf16x8*)(Bb + ((wc & 1) * 64 + n * 16 + (lane & 15)) * 64 + cp);
    }
    char* Ab = sm + buf * 65536 + (wr * 2 + ks) * 8192;
#pragma unroll
    for (int j = 0; j < 4; ++j)
      a[j] = *(const bf16x8*)(Ab + ((mh * 4 + j) * 16 + (lane & 15)) * 64 + cp);
    if (doStage) { stage_sub(stT, stOp, 0, stKs); stage_sub(stT, stOp, 1, stKs); }
    __builtin_amdgcn_s_barrier();
    __builtin_amdgcn_s_setprio(1);
#pragma unroll
    for (int j = 0; j < 4; ++j)
#pragma unroll
      for (int n = 0; n < 4; ++n)
        acc[mh * 4 + j][n] = __builtin_amdgcn_mfma_f32_16x16x32_bf16(a[j], b[n], acc[mh * 4 + j][n], 0, 0, 0);
    __builtin_amdgcn_s_setprio(0);
    if (vm == 6)      asm volatile("s_waitcnt vmcnt(6)" ::: "memory");
    else if (vm == 4) asm volatile("s_waitcnt vmcnt(4)" ::: "memory");
    else if (vm == 0) asm volatile("s_waitcnt vmcnt(0)" ::: "memory");
    __builtin_amdgcn_s_barrier();
  };

  // prologue: stage t0 ks0+ks1, t1 ks0 (12 loads/thread); t0ks0 resident after vmcnt(8)+barrier
  stage_sub(0, 0, 0, 0); stage_sub(0, 0, 1, 0); stage_sub(0, 1, 0, 0); stage_sub(0, 1, 1, 0);
  stage_sub(0, 0, 0, 1); stage_sub(0, 0, 1, 1); stage_sub(0, 1, 0, 1); stage_sub(0, 1, 1, 1);
  stage_sub(1, 0, 0, 0); stage_sub(1, 0, 1, 0); stage_sub(1, 1, 0, 0); stage_sub(1, 1, 1, 0);
  asm volatile("s_waitcnt vmcnt(8)" ::: "memory");
  __builtin_amdgcn_s_barrier();

  // main loop: K-tiles 0..31; vmcnt only at q1 and q3
  for (int i = 0; i < 16; ++i) {
    int t0 = 2 * i;
    phase(0, 0, 0, true, t0 + 1, 0, 1, -1);
    phase(0, 0, 1, true, t0 + 1, 1, 1, 6);
    phase(0, 1, 0, true, t0 + 2, 0, 0, -1);
    phase(0, 1, 1, true, t0 + 2, 1, 0, 6);
    phase(1, 0, 0, true, t0 + 2, 0, 1, -1);
    phase(1, 0, 1, true, t0 + 2, 1, 1, 6);
    phase(1, 1, 0, true, t0 + 3, 0, 0, -1);
    phase(1, 1, 1, true, t0 + 3, 1, 0, 6);
  }
  // tail: tile 32 stages 33-ks1 at q0/q1; vm: q1=6, q3=0 (drain); tile 33 no waits
  phase(0, 0, 0, true, 33, 0, 1, -1);
  phase(0, 0, 1, true, 33, 1, 1, 6);
  phase(0, 1, 0, false, 0, 0, 0, -1);
  phase(0, 1, 1, false, 0, 0, 0, 0);
  phase(1, 0, 0, false, 0, 0, 0, -1);
  phase(1, 0, 1, false, 0, 0, 0, -1);
  phase(1, 1, 0, false, 0, 0, 0, -1);
  phase(1, 1, 1, false, 0, 0, 0, -1);

  // epilogue: bias add, fp32 LDS repack in 2 passes, XOR key (r>>2)&3 << 6,
  // 1024B-coalesced float4 stores
  float* Cs = (float*)sm;
#pragma unroll
  for (int p = 0; p < 2; ++p) {
    __syncthreads();
#pragma unroll
    for (int q = 0; q < 4; ++q) {
#pragma unroll
      for (int nf = 0; nf < 4; ++nf) {
#pragma unroll
        for (int reg = 0; reg < 4; ++reg) {
          int r = wr * 64 + q * 16 + 4 * (lane >> 4) + reg;
          int colb = ((wc * 64 + nf * 16 + (lane & 15)) * 4) ^ (((r >> 2) & 3) << 6);
          *(float*)((char*)Cs + r * 1024 + colb) = acc[p * 4 + q][nf][reg] + bias[nf];
        }
      }
    }
    __syncthreads();
#pragma unroll 4
    for (int it = 0; it < 16; ++it) {
      int v = it * 512 + tid;
      int r = v >> 6, slot = v & 63;
      f32x4 val = *(const f32x4*)((char*)Cs + r * 1024 + ((slot << 4) ^ (((r >> 2) & 3) << 6)));
      long grow = m0 + (r >> 6) * 128 + p * 64 + (r & 63);
      *(f32x4*)(out + grow * DDIM + n0 + slot * 4) = val;
    }
  }
}

// ---------------- launcher ----------------

extern "C" void kernel_launch(void* const* d_in, const int* in_sizes, int n_in,
                              void* d_out, int out_size, void* d_ws, size_t ws_size,
                              hipStream_t stream) {
  const float* x        = (const float*)d_in[0];
  const float* W_base   = (const float*)d_in[1];
  const float* b_base   = (const float*)d_in[2];
  const float* A_s      = (const float*)d_in[3];
  const float* B_s      = (const float*)d_in[4];
  const float* A_r      = (const float*)d_in[5];
  const float* B_r      = (const float*)d_in[6];
  const float* W_router = (const float*)d_in[7];
  const float* b_router = (const float*)d_in[8];
  float* out = (float*)d_out;

  char* ws = (char*)d_ws;
  bf16*  xh    = (bf16*)(ws);                    // 16384*2176*2 = 71,303,168 B
  bf16*  Wcat  = (bf16*)(ws + 71303168);         //  2048*2176*2 =  8,912,896 B
  bf16*  AcT   = (bf16*)(ws + 80216064);         //   128*2048*2 =    524,288 B
  float* gates = (float*)(ws + 80740352);        //   16384*6*4  =    393,216 B
  float* WrT   = (float*)(ws + 81133568);        //    6*2048*4  =     49,152 B

  (void)hipFuncSetAttribute((const void*)gemm256_kernel,
                            hipFuncAttributeMaxDynamicSharedMemorySize, 131072);

  prep_kernel<<<3120, 256, 0, stream>>>(W_base, A_s, A_r, B_s, B_r, W_router, Wcat, AcT, WrT);
  conv_router_kernel<<<TTOK / 4, 256, 0, stream>>>(x, WrT, b_router, xh, gates);
  lora_kernel<<<256, 256, 0, stream>>>(xh, AcT, gates);
  gemm256_kernel<<<512, 512, 131072, stream>>>(xh, Wcat, b_base, out);
}

// Round 16
// 219.413 us; speedup vs baseline: 1.2780x; 1.0422x over previous
//
#include <hip/hip_runtime.h>
#include <hip/hip_bf16.h>

typedef __hip_bfloat16 bf16;
typedef __attribute__((ext_vector_type(8))) __bf16 bf16x8;
typedef __attribute__((ext_vector_type(8))) short s16x8;
typedef __attribute__((ext_vector_type(4))) float f32x4;

#define AS1 __attribute__((address_space(1)))
#define AS3 __attribute__((address_space(3)))

#define DDIM 2048
#define KDIM 2176   // 2048 (x @ W^T) + 128 (hw @ B_cat) fused K-extension
#define TTOK 16384

// ---------------- K1: merged prep ----------------

__global__ __launch_bounds__(256) void prep_kernel(
    const float* __restrict__ W, const float* __restrict__ A_s,
    const float* __restrict__ A_r, const float* __restrict__ Bs,
    const float* __restrict__ Br, const float* __restrict__ Wr,
    bf16* __restrict__ Wcat, bf16* __restrict__ AcT, float* __restrict__ WrT) {
  __shared__ bf16 tl[64][65];
  int bid = blockIdx.x, tid = threadIdx.x;
  if (bid < 1024) {
    int bi = bid >> 5, bj = bid & 31;
    int k0 = bi * 64, n0 = bj * 64;
    int r = tid >> 2, c0 = (tid & 3) << 4;
#pragma unroll
    for (int q = 0; q < 4; ++q) {
      f32x4 v = *(const f32x4*)(W + (long)(k0 + r) * DDIM + n0 + c0 + q * 4);
#pragma unroll
      for (int j = 0; j < 4; ++j) tl[r][c0 + q * 4 + j] = __float2bfloat16(v[j]);
    }
    __syncthreads();
    __align__(16) bf16 o[16];
#pragma unroll
    for (int i = 0; i < 16; ++i) o[i] = tl[c0 + i][r];
    *(s16x8*)(Wcat + (long)(n0 + r) * KDIM + k0 + c0) = *(const s16x8*)o;
    *(s16x8*)(Wcat + (long)(n0 + r) * KDIM + k0 + c0 + 8) = *(const s16x8*)(o + 8);
  } else if (bid < 2048) {
    int idx = (bid - 1024) * 256 + tid;            // over 128*2048
    int c = idx >> 11, d = idx & 2047;
    float v = 0.f;
    if (c < 16)       v = A_s[d * 16 + c];
    else if (c < 112) { int cr = c - 16; v = A_r[((long)(cr >> 4) * DDIM + d) * 16 + (cr & 15)]; }
    AcT[(long)c * DDIM + d] = __float2bfloat16(v);
  } else if (bid < 3072) {
    int idx = (bid - 2048) * 256 + tid;            // over 2048*128
    int n = idx >> 7, c = idx & 127;
    float v = 0.f;
    if (c < 16)       v = Bs[c * DDIM + n];
    else if (c < 112) v = Br[(long)(c - 16) * DDIM + n];
    Wcat[(long)n * KDIM + 2048 + c] = __float2bfloat16(v);
  } else {
    int idx = (bid - 3072) * 256 + tid;            // over 6*2048
    int e = idx >> 11, d = idx & 2047;
    WrT[e * 2048 + d] = Wr[d * 6 + e];
  }
}

// ---------------- K0: fp32->bf16 convert + fp32 router, 4 tokens/block (round-15 proven) ----------

__global__ __launch_bounds__(256) void conv_router_kernel(
    const float* __restrict__ x, const float* __restrict__ WrT, const float* __restrict__ br,
    bf16* __restrict__ xh, float* __restrict__ gates) {
  int tid = threadIdx.x;
  int d0 = tid * 8;
  long t0 = (long)blockIdx.x * 4;

  f32x4 wa[6], wb[6];
#pragma unroll
  for (int e = 0; e < 6; ++e) {
    wa[e] = *(const f32x4*)(WrT + e * 2048 + d0);
    wb[e] = *(const f32x4*)(WrT + e * 2048 + d0 + 4);
  }

  float p[4][6];
#pragma unroll
  for (int s = 0; s < 4; ++s) {
    long t = t0 + s;
    f32x4 v0 = *(const f32x4*)(x + t * DDIM + d0);
    f32x4 v1 = *(const f32x4*)(x + t * DDIM + d0 + 4);
    __align__(16) bf16 tmp[8];
#pragma unroll
    for (int j = 0; j < 4; ++j) {
      tmp[j] = __float2bfloat16(v0[j]);
      tmp[4 + j] = __float2bfloat16(v1[j]);
    }
    *(s16x8*)(xh + t * KDIM + d0) = *(const s16x8*)tmp;
#pragma unroll
    for (int e = 0; e < 6; ++e) {
      float sum = 0.f;
#pragma unroll
      for (int j = 0; j < 4; ++j) sum += v0[j] * wa[e][j];
#pragma unroll
      for (int j = 0; j < 4; ++j) sum += v1[j] * wb[e][j];
      p[s][e] = sum;
    }
  }

#pragma unroll
  for (int off = 32; off > 0; off >>= 1)
#pragma unroll
    for (int s = 0; s < 4; ++s)
#pragma unroll
      for (int e = 0; e < 6; ++e) p[s][e] += __shfl_down(p[s][e], off);

  __shared__ float red[4][4][6];
  int wave = tid >> 6, lane = tid & 63;
  if (lane == 0)
#pragma unroll
    for (int s = 0; s < 4; ++s)
#pragma unroll
      for (int e = 0; e < 6; ++e) red[s][wave][e] = p[s][e];
  __syncthreads();
  if (tid < 4) {
    int s = tid;
    float g[6], mx = -1e30f;
#pragma unroll
    for (int e = 0; e < 6; ++e) {
      g[e] = red[s][0][e] + red[s][1][e] + red[s][2][e] + red[s][3][e] + br[e];
      mx = fmaxf(mx, g[e]);
    }
    float sm = 0.f;
#pragma unroll
    for (int e = 0; e < 6; ++e) { g[e] = __expf(g[e] - mx); sm += g[e]; }
    float inv = 1.f / sm;
#pragma unroll
    for (int e = 0; e < 6; ++e) g[e] *= inv;
    int i1 = 0; float w1 = g[0];
#pragma unroll
    for (int e = 1; e < 6; ++e) if (g[e] > w1) { w1 = g[e]; i1 = e; }
    int i2 = -1; float w2 = -1.f;
#pragma unroll
    for (int e = 0; e < 6; ++e) if (e != i1 && g[e] > w2) { w2 = g[e]; i2 = e; }
#pragma unroll
    for (int e = 0; e < 6; ++e)
      gates[(t0 + s) * 6 + e] = (e == i1) ? w1 : (e == i2) ? w2 : 0.f;
  }
}

// ---------------- staging: [ROWS x 64] bf16 tile, LDS-linear (lora kernel) ----------------

template <int ROWS>
__device__ __forceinline__ void stage_tile(const bf16* __restrict__ g, long rs,
                                           bf16* lds, int wave, int lane) {
#pragma unroll
  for (int i = 0; i < (ROWS >> 5); ++i) {
    int chunk_base = (i * 4 + wave) * 64;
    int byte = (chunk_base + lane) * 16;
    int row = byte >> 7;
    int col = (byte & 127) >> 1;
    __builtin_amdgcn_global_load_lds(
        (const AS1 void*)(g + (long)row * rs + col),
        (AS3 void*)(lds + chunk_base * 8), 16, 0, 0);
  }
}

// ---------------- K2: lora, 32 tokens/block (2-3 blocks/CU), double-buffered ----------------
// 2x2 wave grid: wm = 16-row group, wn = 64-col half (8 frags; cols 112-127 get wgt 0).
// 5 loads/iter -> vmcnt(5); buffer overwrite protected by per-iter end barrier.

__global__ __launch_bounds__(256) void lora_kernel(
    bf16* __restrict__ xh, const bf16* __restrict__ AcT,
    const float* __restrict__ gates) {
  __shared__ __align__(16) short smem[2 * 160 * 64];   // 2 x (32+128) x 64 bf16 = 40 KB
  __shared__ float G[32][6];
  int tid = threadIdx.x, wave = tid >> 6, lane = tid & 63;
  int wm = wave >> 1, wn = wave & 1;
  long m0 = (long)blockIdx.x * 32;

  auto Xbuf = [&](int b) { return (bf16*)smem + b * 160 * 64; };
  auto Bbuf = [&](int b) { return (bf16*)smem + b * 160 * 64 + 32 * 64; };

  stage_tile<32>(xh + m0 * KDIM, KDIM, Xbuf(0), wave, lane);
  stage_tile<128>(AcT, DDIM, Bbuf(0), wave, lane);
  for (int i = tid; i < 192; i += 256) G[i / 6][i % 6] = gates[(m0 + i / 6) * 6 + i % 6];
  __syncthreads();

  f32x4 acc[4];
#pragma unroll
  for (int i = 0; i < 4; ++i) acc[i] = f32x4{0.f, 0.f, 0.f, 0.f};

  for (int kt = 0; kt < 32; ++kt) {
    int cur = kt & 1;
    if (kt < 31) {
      int k1 = (kt + 1) * 64;
      stage_tile<32>(xh + m0 * KDIM + k1, KDIM, Xbuf(cur ^ 1), wave, lane);
      stage_tile<128>(AcT + k1, DDIM, Bbuf(cur ^ 1), wave, lane);
    }
    if (kt > 0) {
      if (kt < 31) asm volatile("s_waitcnt vmcnt(5)" ::: "memory");
      else         asm volatile("s_waitcnt vmcnt(0)" ::: "memory");
      __builtin_amdgcn_sched_barrier(0);
      __builtin_amdgcn_s_barrier();
      __builtin_amdgcn_sched_barrier(0);
    }
    bf16* X_s = Xbuf(cur);
    bf16* B_s = Bbuf(cur);
#pragma unroll
    for (int kk = 0; kk < 2; ++kk) {
      bf16x8 a = *(const bf16x8*)(X_s + (wm * 16 + (lane & 15)) * 64 + kk * 32 + (lane >> 4) * 8);
#pragma unroll
      for (int nr = 0; nr < 4; ++nr) {
        bf16x8 b = *(const bf16x8*)(B_s + (wn * 64 + nr * 16 + (lane & 15)) * 64 + kk * 32 + (lane >> 4) * 8);
        acc[nr] = __builtin_amdgcn_mfma_f32_16x16x32_bf16(a, b, acc[nr], 0, 0, 0);
      }
    }
    __builtin_amdgcn_sched_barrier(0);
    __builtin_amdgcn_s_barrier();
  }

  // epilogue: gate-scale into LDS [32][128], then coalesced 16B global stores
  bf16* H = (bf16*)smem;
#pragma unroll
  for (int nr = 0; nr < 4; ++nr) {
    int c = wn * 64 + nr * 16 + (lane & 15);
#pragma unroll
    for (int reg = 0; reg < 4; ++reg) {
      int tl = wm * 16 + 4 * (lane >> 4) + reg;
      float wgt = (c < 16) ? 1.f : (c < 112 ? G[tl][(c - 16) >> 4] : 0.f);
      H[tl * 128 + c] = __float2bfloat16(acc[nr][reg] * wgt);
    }
  }
  __syncthreads();
#pragma unroll
  for (int p = 0; p < 2; ++p) {
    int v = p * 256 + tid;
    int row = v >> 4, ch = (v & 15) * 8;
    *(s16x8*)(xh + (m0 + row) * KDIM + 2048 + ch) = *(const s16x8*)(H + row * 128 + ch);
  }
}

// ---------------- kernel B v11: 8-phase body, 2 barriers per K-tile ----------------
// Barrier audit: residency needs only q1/q3 vmcnt(6)+barrier (FIFO chain re-derived per
// load-event); overwrite regions (A-ks0/B-ks0 at q2/q3 stages) are fenced by the q1-end
// barrier; first-of-phase barriers and q0/q2-end barriers removed. Waves skid freely
// within 2-phase windows -> LDS and MFMA pipes overlap.

__global__ __launch_bounds__(512, 2) void gemm256_kernel(
    const bf16* __restrict__ xh, const bf16* __restrict__ Wcat,
    const float* __restrict__ b_base, float* __restrict__ out) {
  extern __shared__ char sm[];
  int tid = threadIdx.x, wave = tid >> 6, lane = tid & 63;
  int wr = wave >> 2, wc = wave & 3;   // 2x4 wave grid; per-wave 128 x 64 output

  // XCD-bijective swizzle (nwg = 512, divisible by 8)
  int bid = blockIdx.x;
  int cpx = gridDim.x >> 3;
  int swz = (bid & 7) * cpx + (bid >> 3);
  long m0 = (long)(swz >> 3) * 256;    // 64 x 8 grid
  int n0 = (swz & 7) * 256;

  // proven-0-conflict frag constants: row = lane&15, slot = lane>>4, XOR ((lane>>1)&3)<<4
  int cp = ((lane >> 4) << 4) ^ (((lane >> 1) & 3) << 4);

  float bias[4];
#pragma unroll
  for (int nf = 0; nf < 4; ++nf) bias[nf] = b_base[n0 + wc * 64 + nf * 16 + (lane & 15)];

  f32x4 acc[8][4];
#pragma unroll
  for (int i = 0; i < 8; ++i)
#pragma unroll
    for (int j = 0; j < 4; ++j) acc[i][j] = f32x4{0.f, 0.f, 0.f, 0.f};

  const bf16* Agl = xh + m0 * KDIM;
  const bf16* Bgl = Wcat + (long)n0 * KDIM;

  // stage one 8KB subtile (op: 0=A,1=B; half h; ks s) of K-tile t: 1 load/thread
  auto stage_sub = [&](int t, int op, int h, int s) {
    int row = tid >> 2;
    int scol = ((((tid & 3) << 4) ^ (((row >> 1) & 3) << 4)) >> 1);
    const bf16* src = (op ? Bgl : Agl) + (long)(h * 128 + row) * KDIM + t * 64 + s * 32 + scol;
    char* dst = sm + (t & 1) * 65536 + op * 32768 + (h * 2 + s) * 8192 + tid * 16;
    __builtin_amdgcn_global_load_lds((const AS1 void*)src, (AS3 void*)dst, 16, 0, 0);
  };

  bf16x8 a[4], b[4];

  // phase: quadrant (ks, mh); optional stage of 2 subtiles; counted vmcnt; optional barrier
  auto phase = [&](int buf, int ks, int mh, bool doStage, int stT, int stOp, int stKs,
                   int vm, bool bar) {
    if (mh == 0) {
      char* Bb = sm + buf * 65536 + 32768 + ((wc >> 1) * 2 + ks) * 8192;
#pragma unroll
      for (int n = 0; n < 4; ++n)
        b[n] = *(const bf16x8*)(Bb + ((wc & 1) * 64 + n * 16 + (lane & 15)) * 64 + cp);
    }
    char* Ab = sm + buf * 65536 + (wr * 2 + ks) * 8192;
#pragma unroll
    for (int j = 0; j < 4; ++j)
      a[j] = *(const bf16x8*)(Ab + ((mh * 4 + j) * 16 + (lane & 15)) * 64 + cp);
    if (doStage) { stage_sub(stT, stOp, 0, stKs); stage_sub(stT, stOp, 1, stKs); }
    __builtin_amdgcn_s_setprio(1);
#pragma unroll
    for (int j = 0; j < 4; ++j)
#pragma unroll
      for (int n = 0; n < 4; ++n)
        acc[mh * 4 + j][n] = __builtin_amdgcn_mfma_f32_16x16x32_bf16(a[j], b[n], acc[mh * 4 + j][n], 0, 0, 0);
    __builtin_amdgcn_s_setprio(0);
    if (vm == 6)      asm volatile("s_waitcnt vmcnt(6)" ::: "memory");
    else if (vm == 0) asm volatile("s_waitcnt vmcnt(0)" ::: "memory");
    if (bar) __builtin_amdgcn_s_barrier();
  };

  // prologue: stage t0 ks0+ks1, t1 ks0 (12 loads/thread); t0 resident after vmcnt(8)... full
  stage_sub(0, 0, 0, 0); stage_sub(0, 0, 1, 0); stage_sub(0, 1, 0, 0); stage_sub(0, 1, 1, 0);
  stage_sub(0, 0, 0, 1); stage_sub(0, 0, 1, 1); stage_sub(0, 1, 0, 1); stage_sub(0, 1, 1, 1);
  stage_sub(1, 0, 0, 0); stage_sub(1, 0, 1, 0); stage_sub(1, 1, 0, 0); stage_sub(1, 1, 1, 0);
  asm volatile("s_waitcnt vmcnt(8)" ::: "memory");
  __builtin_amdgcn_s_barrier();

  // main loop: K-tiles 0..31; vmcnt(6)+barrier at q1 and q3 ONLY
  for (int i = 0; i < 16; ++i) {
    int t0 = 2 * i;
    phase(0, 0, 0, true, t0 + 1, 0, 1, -1, false);
    phase(0, 0, 1, true, t0 + 1, 1, 1, 6, true);
    phase(0, 1, 0, true, t0 + 2, 0, 0, -1, false);
    phase(0, 1, 1, true, t0 + 2, 1, 0, 6, true);
    phase(1, 0, 0, true, t0 + 2, 0, 1, -1, false);
    phase(1, 0, 1, true, t0 + 2, 1, 1, 6, true);
    phase(1, 1, 0, true, t0 + 3, 0, 0, -1, false);
    phase(1, 1, 1, true, t0 + 3, 1, 0, 6, true);
  }
  // tail: tile 32 stages 33-ks1 at q0/q1; q1 vm6+bar, q3 vm0+bar; tile 33 free-run
  phase(0, 0, 0, true, 33, 0, 1, -1, false);
  phase(0, 0, 1, true, 33, 1, 1, 6, true);
  phase(0, 1, 0, false, 0, 0, 0, -1, false);
  phase(0, 1, 1, false, 0, 0, 0, 0, true);
  phase(1, 0, 0, false, 0, 0, 0, -1, false);
  phase(1, 0, 1, false, 0, 0, 0, -1, false);
  phase(1, 1, 0, false, 0, 0, 0, -1, false);
  phase(1, 1, 1, false, 0, 0, 0, -1, false);

  // epilogue: bias add, fp32 LDS repack in 2 passes, XOR key (r>>2)&3 << 6,
  // 1024B-coalesced float4 stores
  float* Cs = (float*)sm;
#pragma unroll
  for (int p = 0; p < 2; ++p) {
    __syncthreads();
#pragma unroll
    for (int q = 0; q < 4; ++q) {
#pragma unroll
      for (int nf = 0; nf < 4; ++nf) {
#pragma unroll
        for (int reg = 0; reg < 4; ++reg) {
          int r = wr * 64 + q * 16 + 4 * (lane >> 4) + reg;
          int colb = ((wc * 64 + nf * 16 + (lane & 15)) * 4) ^ (((r >> 2) & 3) << 6);
          *(float*)((char*)Cs + r * 1024 + colb) = acc[p * 4 + q][nf][reg] + bias[nf];
        }
      }
    }
    __syncthreads();
#pragma unroll 4
    for (int it = 0; it < 16; ++it) {
      int v = it * 512 + tid;
      int r = v >> 6, slot = v & 63;
      f32x4 val = *(const f32x4*)((char*)Cs + r * 1024 + ((slot << 4) ^ (((r >> 2) & 3) << 6)));
      long grow = m0 + (r >> 6) * 128 + p * 64 + (r & 63);
      *(f32x4*)(out + grow * DDIM + n0 + slot * 4) = val;
    }
  }
}

// ---------------- launcher ----------------

extern "C" void kernel_launch(void* const* d_in, const int* in_sizes, int n_in,
                              void* d_out, int out_size, void* d_ws, size_t ws_size,
                              hipStream_t stream) {
  const float* x        = (const float*)d_in[0];
  const float* W_base   = (const float*)d_in[1];
  const float* b_base   = (const float*)d_in[2];
  const float* A_s      = (const float*)d_in[3];
  const float* B_s      = (const float*)d_in[4];
  const float* A_r      = (const float*)d_in[5];
  const float* B_r      = (const float*)d_in[6];
  const float* W_router = (const float*)d_in[7];
  const float* b_router = (const float*)d_in[8];
  float* out = (float*)d_out;

  char* ws = (char*)d_ws;
  bf16*  xh    = (bf16*)(ws);                    // 16384*2176*2 = 71,303,168 B
  bf16*  Wcat  = (bf16*)(ws + 71303168);         //  2048*2176*2 =  8,912,896 B
  bf16*  AcT   = (bf16*)(ws + 80216064);         //   128*2048*2 =    524,288 B
  float* gates = (float*)(ws + 80740352);        //   16384*6*4  =    393,216 B
  float* WrT   = (float*)(ws + 81133568);        //    6*2048*4  =     49,152 B

  (void)hipFuncSetAttribute((const void*)gemm256_kernel,
                            hipFuncAttributeMaxDynamicSharedMemorySize, 131072);

  prep_kernel<<<3120, 256, 0, stream>>>(W_base, A_s, A_r, B_s, B_r, W_router, Wcat, AcT, WrT);
  conv_router_kernel<<<TTOK / 4, 256, 0, stream>>>(x, WrT, b_router, xh, gates);
  lora_kernel<<<512, 256, 0, stream>>>(xh, AcT, gates);
  gemm256_kernel<<<512, 512, 131072, stream>>>(xh, Wcat, b_base, out);
}

// Round 17
// 219.271 us; speedup vs baseline: 1.2789x; 1.0007x over previous
//
#include <hip/hip_runtime.h>
#include <hip/hip_bf16.h>

typedef __hip_bfloat16 bf16;
typedef __attribute__((ext_vector_type(8))) __bf16 bf16x8;
typedef __attribute__((ext_vector_type(8))) short s16x8;
typedef __attribute__((ext_vector_type(4))) float f32x4;

#define AS1 __attribute__((address_space(1)))
#define AS3 __attribute__((address_space(3)))

#define DDIM 2048
#define KDIM 2176   // 2048 (x @ W^T) + 128 (hw @ B_cat) fused K-extension
#define TTOK 16384

// ---------------- K1: merged prep ----------------

__global__ __launch_bounds__(256) void prep_kernel(
    const float* __restrict__ W, const float* __restrict__ A_s,
    const float* __restrict__ A_r, const float* __restrict__ Bs,
    const float* __restrict__ Br, const float* __restrict__ Wr,
    bf16* __restrict__ Wcat, bf16* __restrict__ AcT, float* __restrict__ WrT) {
  __shared__ bf16 tl[64][65];
  int bid = blockIdx.x, tid = threadIdx.x;
  if (bid < 1024) {
    int bi = bid >> 5, bj = bid & 31;
    int k0 = bi * 64, n0 = bj * 64;
    int r = tid >> 2, c0 = (tid & 3) << 4;
#pragma unroll
    for (int q = 0; q < 4; ++q) {
      f32x4 v = *(const f32x4*)(W + (long)(k0 + r) * DDIM + n0 + c0 + q * 4);
#pragma unroll
      for (int j = 0; j < 4; ++j) tl[r][c0 + q * 4 + j] = __float2bfloat16(v[j]);
    }
    __syncthreads();
    __align__(16) bf16 o[16];
#pragma unroll
    for (int i = 0; i < 16; ++i) o[i] = tl[c0 + i][r];
    *(s16x8*)(Wcat + (long)(n0 + r) * KDIM + k0 + c0) = *(const s16x8*)o;
    *(s16x8*)(Wcat + (long)(n0 + r) * KDIM + k0 + c0 + 8) = *(const s16x8*)(o + 8);
  } else if (bid < 2048) {
    int idx = (bid - 1024) * 256 + tid;            // over 128*2048
    int c = idx >> 11, d = idx & 2047;
    float v = 0.f;
    if (c < 16)       v = A_s[d * 16 + c];
    else if (c < 112) { int cr = c - 16; v = A_r[((long)(cr >> 4) * DDIM + d) * 16 + (cr & 15)]; }
    AcT[(long)c * DDIM + d] = __float2bfloat16(v);
  } else if (bid < 3072) {
    int idx = (bid - 2048) * 256 + tid;            // over 2048*128
    int n = idx >> 7, c = idx & 127;
    float v = 0.f;
    if (c < 16)       v = Bs[c * DDIM + n];
    else if (c < 112) v = Br[(long)(c - 16) * DDIM + n];
    Wcat[(long)n * KDIM + 2048 + c] = __float2bfloat16(v);
  } else {
    int idx = (bid - 3072) * 256 + tid;            // over 6*2048
    int e = idx >> 11, d = idx & 2047;
    WrT[e * 2048 + d] = Wr[d * 6 + e];
  }
}

// ---------------- K0: fp32->bf16 convert + fp32 router, 4 tokens/block (round-15 proven) ----------

__global__ __launch_bounds__(256) void conv_router_kernel(
    const float* __restrict__ x, const float* __restrict__ WrT, const float* __restrict__ br,
    bf16* __restrict__ xh, float* __restrict__ gates) {
  int tid = threadIdx.x;
  int d0 = tid * 8;
  long t0 = (long)blockIdx.x * 4;

  f32x4 wa[6], wb[6];
#pragma unroll
  for (int e = 0; e < 6; ++e) {
    wa[e] = *(const f32x4*)(WrT + e * 2048 + d0);
    wb[e] = *(const f32x4*)(WrT + e * 2048 + d0 + 4);
  }

  float p[4][6];
#pragma unroll
  for (int s = 0; s < 4; ++s) {
    long t = t0 + s;
    f32x4 v0 = *(const f32x4*)(x + t * DDIM + d0);
    f32x4 v1 = *(const f32x4*)(x + t * DDIM + d0 + 4);
    __align__(16) bf16 tmp[8];
#pragma unroll
    for (int j = 0; j < 4; ++j) {
      tmp[j] = __float2bfloat16(v0[j]);
      tmp[4 + j] = __float2bfloat16(v1[j]);
    }
    *(s16x8*)(xh + t * KDIM + d0) = *(const s16x8*)tmp;
#pragma unroll
    for (int e = 0; e < 6; ++e) {
      float sum = 0.f;
#pragma unroll
      for (int j = 0; j < 4; ++j) sum += v0[j] * wa[e][j];
#pragma unroll
      for (int j = 0; j < 4; ++j) sum += v1[j] * wb[e][j];
      p[s][e] = sum;
    }
  }

#pragma unroll
  for (int off = 32; off > 0; off >>= 1)
#pragma unroll
    for (int s = 0; s < 4; ++s)
#pragma unroll
      for (int e = 0; e < 6; ++e) p[s][e] += __shfl_down(p[s][e], off);

  __shared__ float red[4][4][6];
  int wave = tid >> 6, lane = tid & 63;
  if (lane == 0)
#pragma unroll
    for (int s = 0; s < 4; ++s)
#pragma unroll
      for (int e = 0; e < 6; ++e) red[s][wave][e] = p[s][e];
  __syncthreads();
  if (tid < 4) {
    int s = tid;
    float g[6], mx = -1e30f;
#pragma unroll
    for (int e = 0; e < 6; ++e) {
      g[e] = red[s][0][e] + red[s][1][e] + red[s][2][e] + red[s][3][e] + br[e];
      mx = fmaxf(mx, g[e]);
    }
    float sm = 0.f;
#pragma unroll
    for (int e = 0; e < 6; ++e) { g[e] = __expf(g[e] - mx); sm += g[e]; }
    float inv = 1.f / sm;
#pragma unroll
    for (int e = 0; e < 6; ++e) g[e] *= inv;
    int i1 = 0; float w1 = g[0];
#pragma unroll
    for (int e = 1; e < 6; ++e) if (g[e] > w1) { w1 = g[e]; i1 = e; }
    int i2 = -1; float w2 = -1.f;
#pragma unroll
    for (int e = 0; e < 6; ++e) if (e != i1 && g[e] > w2) { w2 = g[e]; i2 = e; }
#pragma unroll
    for (int e = 0; e < 6; ++e)
      gates[(t0 + s) * 6 + e] = (e == i1) ? w1 : (e == i2) ? w2 : 0.f;
  }
}

// ---------------- staging: [ROWS x 64] bf16 tile, LDS-linear (lora kernel) ----------------

template <int ROWS>
__device__ __forceinline__ void stage_tile(const bf16* __restrict__ g, long rs,
                                           bf16* lds, int wave, int lane) {
#pragma unroll
  for (int i = 0; i < (ROWS >> 5); ++i) {
    int chunk_base = (i * 4 + wave) * 64;
    int byte = (chunk_base + lane) * 16;
    int row = byte >> 7;
    int col = (byte & 127) >> 1;
    __builtin_amdgcn_global_load_lds(
        (const AS1 void*)(g + (long)row * rs + col),
        (AS3 void*)(lds + chunk_base * 8), 16, 0, 0);
  }
}

// ---------------- K2: lora, 32 tokens/block (round-16 proven) ----------------

__global__ __launch_bounds__(256) void lora_kernel(
    bf16* __restrict__ xh, const bf16* __restrict__ AcT,
    const float* __restrict__ gates) {
  __shared__ __align__(16) short smem[2 * 160 * 64];   // 40 KB
  __shared__ float G[32][6];
  int tid = threadIdx.x, wave = tid >> 6, lane = tid & 63;
  int wm = wave >> 1, wn = wave & 1;
  long m0 = (long)blockIdx.x * 32;

  auto Xbuf = [&](int b) { return (bf16*)smem + b * 160 * 64; };
  auto Bbuf = [&](int b) { return (bf16*)smem + b * 160 * 64 + 32 * 64; };

  stage_tile<32>(xh + m0 * KDIM, KDIM, Xbuf(0), wave, lane);
  stage_tile<128>(AcT, DDIM, Bbuf(0), wave, lane);
  for (int i = tid; i < 192; i += 256) G[i / 6][i % 6] = gates[(m0 + i / 6) * 6 + i % 6];
  __syncthreads();

  f32x4 acc[4];
#pragma unroll
  for (int i = 0; i < 4; ++i) acc[i] = f32x4{0.f, 0.f, 0.f, 0.f};

  for (int kt = 0; kt < 32; ++kt) {
    int cur = kt & 1;
    if (kt < 31) {
      int k1 = (kt + 1) * 64;
      stage_tile<32>(xh + m0 * KDIM + k1, KDIM, Xbuf(cur ^ 1), wave, lane);
      stage_tile<128>(AcT + k1, DDIM, Bbuf(cur ^ 1), wave, lane);
    }
    if (kt > 0) {
      if (kt < 31) asm volatile("s_waitcnt vmcnt(5)" ::: "memory");
      else         asm volatile("s_waitcnt vmcnt(0)" ::: "memory");
      __builtin_amdgcn_sched_barrier(0);
      __builtin_amdgcn_s_barrier();
      __builtin_amdgcn_sched_barrier(0);
    }
    bf16* X_s = Xbuf(cur);
    bf16* B_s = Bbuf(cur);
#pragma unroll
    for (int kk = 0; kk < 2; ++kk) {
      bf16x8 a = *(const bf16x8*)(X_s + (wm * 16 + (lane & 15)) * 64 + kk * 32 + (lane >> 4) * 8);
#pragma unroll
      for (int nr = 0; nr < 4; ++nr) {
        bf16x8 b = *(const bf16x8*)(B_s + (wn * 64 + nr * 16 + (lane & 15)) * 64 + kk * 32 + (lane >> 4) * 8);
        acc[nr] = __builtin_amdgcn_mfma_f32_16x16x32_bf16(a, b, acc[nr], 0, 0, 0);
      }
    }
    __builtin_amdgcn_sched_barrier(0);
    __builtin_amdgcn_s_barrier();
  }

  bf16* H = (bf16*)smem;
#pragma unroll
  for (int nr = 0; nr < 4; ++nr) {
    int c = wn * 64 + nr * 16 + (lane & 15);
#pragma unroll
    for (int reg = 0; reg < 4; ++reg) {
      int tl = wm * 16 + 4 * (lane >> 4) + reg;
      float wgt = (c < 16) ? 1.f : (c < 112 ? G[tl][(c - 16) >> 4] : 0.f);
      H[tl * 128 + c] = __float2bfloat16(acc[nr][reg] * wgt);
    }
  }
  __syncthreads();
#pragma unroll
  for (int p = 0; p < 2; ++p) {
    int v = p * 256 + tid;
    int row = v >> 4, ch = (v & 15) * 8;
    *(s16x8*)(xh + (m0 + row) * KDIM + 2048 + ch) = *(const s16x8*)(H + row * 128 + ch);
  }
}

// ---------------- kernel B v12: v11 with deadline-exact vmcnt (8,8) ----------------
// FIFO audit (steady state, 12 outstanding before each wait):
//  q1-end: need ks1(t) = t-1 q0/q1 loads = positions 8-11  -> vm8 drains exactly them;
//  q3-end: need ks0(t+1) = t-1 q2/q3 loads = positions 8-11 -> vm8.
// Drained loads are 4-5 phases (~1000-1250 cyc) old -> past L3/HBM latency, waits ~free.
// Prologue: tile-0 audit passes with vm8 (drains land on prologue ks1 / t1-ks0 groups).
// Tail: t32 q1 vm8 (ks1(32) at pos 8-11); t32 q3 vm0 full drain covers all t33 reads.

__global__ __launch_bounds__(512, 2) void gemm256_kernel(
    const bf16* __restrict__ xh, const bf16* __restrict__ Wcat,
    const float* __restrict__ b_base, float* __restrict__ out) {
  extern __shared__ char sm[];
  int tid = threadIdx.x, wave = tid >> 6, lane = tid & 63;
  int wr = wave >> 2, wc = wave & 3;   // 2x4 wave grid; per-wave 128 x 64 output

  // XCD-bijective swizzle (nwg = 512, divisible by 8)
  int bid = blockIdx.x;
  int cpx = gridDim.x >> 3;
  int swz = (bid & 7) * cpx + (bid >> 3);
  long m0 = (long)(swz >> 3) * 256;    // 64 x 8 grid
  int n0 = (swz & 7) * 256;

  // proven-0-conflict frag constants: row = lane&15, slot = lane>>4, XOR ((lane>>1)&3)<<4
  int cp = ((lane >> 4) << 4) ^ (((lane >> 1) & 3) << 4);

  float bias[4];
#pragma unroll
  for (int nf = 0; nf < 4; ++nf) bias[nf] = b_base[n0 + wc * 64 + nf * 16 + (lane & 15)];

  f32x4 acc[8][4];
#pragma unroll
  for (int i = 0; i < 8; ++i)
#pragma unroll
    for (int j = 0; j < 4; ++j) acc[i][j] = f32x4{0.f, 0.f, 0.f, 0.f};

  const bf16* Agl = xh + m0 * KDIM;
  const bf16* Bgl = Wcat + (long)n0 * KDIM;

  // stage one 8KB subtile (op: 0=A,1=B; half h; ks s) of K-tile t: 1 load/thread
  auto stage_sub = [&](int t, int op, int h, int s) {
    int row = tid >> 2;
    int scol = ((((tid & 3) << 4) ^ (((row >> 1) & 3) << 4)) >> 1);
    const bf16* src = (op ? Bgl : Agl) + (long)(h * 128 + row) * KDIM + t * 64 + s * 32 + scol;
    char* dst = sm + (t & 1) * 65536 + op * 32768 + (h * 2 + s) * 8192 + tid * 16;
    __builtin_amdgcn_global_load_lds((const AS1 void*)src, (AS3 void*)dst, 16, 0, 0);
  };

  bf16x8 a[4], b[4];

  // phase: quadrant (ks, mh); optional stage of 2 subtiles; counted vmcnt; optional barrier
  auto phase = [&](int buf, int ks, int mh, bool doStage, int stT, int stOp, int stKs,
                   int vm, bool bar) {
    if (mh == 0) {
      char* Bb = sm + buf * 65536 + 32768 + ((wc >> 1) * 2 + ks) * 8192;
#pragma unroll
      for (int n = 0; n < 4; ++n)
        b[n] = *(const bf16x8*)(Bb + ((wc & 1) * 64 + n * 16 + (lane & 15)) * 64 + cp);
    }
    char* Ab = sm + buf * 65536 + (wr * 2 + ks) * 8192;
#pragma unroll
    for (int j = 0; j < 4; ++j)
      a[j] = *(const bf16x8*)(Ab + ((mh * 4 + j) * 16 + (lane & 15)) * 64 + cp);
    if (doStage) { stage_sub(stT, stOp, 0, stKs); stage_sub(stT, stOp, 1, stKs); }
    __builtin_amdgcn_s_setprio(1);
#pragma unroll
    for (int j = 0; j < 4; ++j)
#pragma unroll
      for (int n = 0; n < 4; ++n)
        acc[mh * 4 + j][n] = __builtin_amdgcn_mfma_f32_16x16x32_bf16(a[j], b[n], acc[mh * 4 + j][n], 0, 0, 0);
    __builtin_amdgcn_s_setprio(0);
    if (vm == 8)      asm volatile("s_waitcnt vmcnt(8)" ::: "memory");
    else if (vm == 0) asm volatile("s_waitcnt vmcnt(0)" ::: "memory");
    if (bar) __builtin_amdgcn_s_barrier();
  };

  // prologue: stage t0 ks0+ks1, t1 ks0 (12 loads/thread); t0ks0 resident after vmcnt(8)+barrier
  stage_sub(0, 0, 0, 0); stage_sub(0, 0, 1, 0); stage_sub(0, 1, 0, 0); stage_sub(0, 1, 1, 0);
  stage_sub(0, 0, 0, 1); stage_sub(0, 0, 1, 1); stage_sub(0, 1, 0, 1); stage_sub(0, 1, 1, 1);
  stage_sub(1, 0, 0, 0); stage_sub(1, 0, 1, 0); stage_sub(1, 1, 0, 0); stage_sub(1, 1, 1, 0);
  asm volatile("s_waitcnt vmcnt(8)" ::: "memory");
  __builtin_amdgcn_s_barrier();

  // main loop: K-tiles 0..31; vmcnt(8)+barrier at q1 and q3 ONLY
  for (int i = 0; i < 16; ++i) {
    int t0 = 2 * i;
    phase(0, 0, 0, true, t0 + 1, 0, 1, -1, false);
    phase(0, 0, 1, true, t0 + 1, 1, 1, 8, true);
    phase(0, 1, 0, true, t0 + 2, 0, 0, -1, false);
    phase(0, 1, 1, true, t0 + 2, 1, 0, 8, true);
    phase(1, 0, 0, true, t0 + 2, 0, 1, -1, false);
    phase(1, 0, 1, true, t0 + 2, 1, 1, 8, true);
    phase(1, 1, 0, true, t0 + 3, 0, 0, -1, false);
    phase(1, 1, 1, true, t0 + 3, 1, 0, 8, true);
  }
  // tail: tile 32 stages 33-ks1 at q0/q1; q1 vm8+bar, q3 vm0+bar; tile 33 free-run
  phase(0, 0, 0, true, 33, 0, 1, -1, false);
  phase(0, 0, 1, true, 33, 1, 1, 8, true);
  phase(0, 1, 0, false, 0, 0, 0, -1, false);
  phase(0, 1, 1, false, 0, 0, 0, 0, true);
  phase(1, 0, 0, false, 0, 0, 0, -1, false);
  phase(1, 0, 1, false, 0, 0, 0, -1, false);
  phase(1, 1, 0, false, 0, 0, 0, -1, false);
  phase(1, 1, 1, false, 0, 0, 0, -1, false);

  // epilogue: bias add, fp32 LDS repack in 2 passes, XOR key (r>>2)&3 << 6,
  // 1024B-coalesced float4 stores
  float* Cs = (float*)sm;
#pragma unroll
  for (int p = 0; p < 2; ++p) {
    __syncthreads();
#pragma unroll
    for (int q = 0; q < 4; ++q) {
#pragma unroll
      for (int nf = 0; nf < 4; ++nf) {
#pragma unroll
        for (int reg = 0; reg < 4; ++reg) {
          int r = wr * 64 + q * 16 + 4 * (lane >> 4) + reg;
          int colb = ((wc * 64 + nf * 16 + (lane & 15)) * 4) ^ (((r >> 2) & 3) << 6);
          *(float*)((char*)Cs + r * 1024 + colb) = acc[p * 4 + q][nf][reg] + bias[nf];
        }
      }
    }
    __syncthreads();
#pragma unroll 4
    for (int it = 0; it < 16; ++it) {
      int v = it * 512 + tid;
      int r = v >> 6, slot = v & 63;
      f32x4 val = *(const f32x4*)((char*)Cs + r * 1024 + ((slot << 4) ^ (((r >> 2) & 3) << 6)));
      long grow = m0 + (r >> 6) * 128 + p * 64 + (r & 63);
      *(f32x4*)(out + grow * DDIM + n0 + slot * 4) = val;
    }
  }
}

// ---------------- launcher ----------------

extern "C" void kernel_launch(void* const* d_in, const int* in_sizes, int n_in,
                              void* d_out, int out_size, void* d_ws, size_t ws_size,
                              hipStream_t stream) {
  const float* x        = (const float*)d_in[0];
  const float* W_base   = (const float*)d_in[1];
  const float* b_base   = (const float*)d_in[2];
  const float* A_s      = (const float*)d_in[3];
  const float* B_s      = (const float*)d_in[4];
  const float* A_r      = (const float*)d_in[5];
  const float* B_r      = (const float*)d_in[6];
  const float* W_router = (const float*)d_in[7];
  const float* b_router = (const float*)d_in[8];
  float* out = (float*)d_out;

  char* ws = (char*)d_ws;
  bf16*  xh    = (bf16*)(ws);                    // 16384*2176*2 = 71,303,168 B
  bf16*  Wcat  = (bf16*)(ws + 71303168);         //  2048*2176*2 =  8,912,896 B
  bf16*  AcT   = (bf16*)(ws + 80216064);         //   128*2048*2 =    524,288 B
  float* gates = (float*)(ws + 80740352);        //   16384*6*4  =    393,216 B
  float* WrT   = (float*)(ws + 81133568);        //    6*2048*4  =     49,152 B

  (void)hipFuncSetAttribute((const void*)gemm256_kernel,
                            hipFuncAttributeMaxDynamicSharedMemorySize, 131072);

  prep_kernel<<<3120, 256, 0, stream>>>(W_base, A_s, A_r, B_s, B_r, W_router, Wcat, AcT, WrT);
  conv_router_kernel<<<TTOK / 4, 256, 0, stream>>>(x, WrT, b_router, xh, gates);
  lora_kernel<<<512, 256, 0, stream>>>(xh, AcT, gates);
  gemm256_kernel<<<512, 512, 131072, stream>>>(xh, Wcat, b_base, out);
}

// Round 18
// 215.506 us; speedup vs baseline: 1.3012x; 1.0175x over previous
//
#include <hip/hip_runtime.h>
#include <hip/hip_bf16.h>

typedef __hip_bfloat16 bf16;
typedef __attribute__((ext_vector_type(8))) __bf16 bf16x8;
typedef __attribute__((ext_vector_type(8))) short s16x8;
typedef __attribute__((ext_vector_type(4))) float f32x4;

#define AS1 __attribute__((address_space(1)))
#define AS3 __attribute__((address_space(3)))

#define DDIM 2048
#define KDIM 2176   // 2048 (x @ W^T) + 128 (hw @ B_cat) fused K-extension
#define TTOK 16384

// ---------------- K0: tiny WrT transpose (only dependency conv has on weights) ----------------

__global__ __launch_bounds__(256) void wrt_kernel(const float* __restrict__ Wr,
                                                  float* __restrict__ WrT) {
  int idx = blockIdx.x * 256 + threadIdx.x;      // 48 blocks: 6*2048
  int e = idx >> 11, d = idx & 2047;
  WrT[e * 2048 + d] = Wr[d * 6 + e];
}

// ---------------- K1 (merged): conv_router (blocks 0-4095) + weight prep (4096-7167) ----------
// conv math byte-identical to round-15 proven version; prep blocks independent.

__global__ __launch_bounds__(256) void conv_prep_kernel(
    const float* __restrict__ x, const float* __restrict__ WrT, const float* __restrict__ br,
    bf16* __restrict__ xh, float* __restrict__ gates,
    const float* __restrict__ W, const float* __restrict__ A_s,
    const float* __restrict__ A_r, const float* __restrict__ Bs,
    const float* __restrict__ Br, bf16* __restrict__ Wcat, bf16* __restrict__ AcT) {
  int bid = blockIdx.x, tid = threadIdx.x;

  if (bid < 4096) {
    // ---- conv_router: fp32->bf16 convert + fp32 router, 4 tokens/block ----
    int d0 = tid * 8;
    long t0 = (long)bid * 4;

    f32x4 wa[6], wb[6];
#pragma unroll
    for (int e = 0; e < 6; ++e) {
      wa[e] = *(const f32x4*)(WrT + e * 2048 + d0);
      wb[e] = *(const f32x4*)(WrT + e * 2048 + d0 + 4);
    }

    float p[4][6];
#pragma unroll
    for (int s = 0; s < 4; ++s) {
      long t = t0 + s;
      f32x4 v0 = *(const f32x4*)(x + t * DDIM + d0);
      f32x4 v1 = *(const f32x4*)(x + t * DDIM + d0 + 4);
      __align__(16) bf16 tmp[8];
#pragma unroll
      for (int j = 0; j < 4; ++j) {
        tmp[j] = __float2bfloat16(v0[j]);
        tmp[4 + j] = __float2bfloat16(v1[j]);
      }
      *(s16x8*)(xh + t * KDIM + d0) = *(const s16x8*)tmp;
#pragma unroll
      for (int e = 0; e < 6; ++e) {
        float sum = 0.f;
#pragma unroll
        for (int j = 0; j < 4; ++j) sum += v0[j] * wa[e][j];
#pragma unroll
        for (int j = 0; j < 4; ++j) sum += v1[j] * wb[e][j];
        p[s][e] = sum;
      }
    }

#pragma unroll
    for (int off = 32; off > 0; off >>= 1)
#pragma unroll
      for (int s = 0; s < 4; ++s)
#pragma unroll
        for (int e = 0; e < 6; ++e) p[s][e] += __shfl_down(p[s][e], off);

    __shared__ float red[4][4][6];
    int wave = tid >> 6, lane = tid & 63;
    if (lane == 0)
#pragma unroll
      for (int s = 0; s < 4; ++s)
#pragma unroll
        for (int e = 0; e < 6; ++e) red[s][wave][e] = p[s][e];
    __syncthreads();
    if (tid < 4) {
      int s = tid;
      float g[6], mx = -1e30f;
#pragma unroll
      for (int e = 0; e < 6; ++e) {
        g[e] = red[s][0][e] + red[s][1][e] + red[s][2][e] + red[s][3][e] + br[e];
        mx = fmaxf(mx, g[e]);
      }
      float sm = 0.f;
#pragma unroll
      for (int e = 0; e < 6; ++e) { g[e] = __expf(g[e] - mx); sm += g[e]; }
      float inv = 1.f / sm;
#pragma unroll
      for (int e = 0; e < 6; ++e) g[e] *= inv;
      int i1 = 0; float w1 = g[0];
#pragma unroll
      for (int e = 1; e < 6; ++e) if (g[e] > w1) { w1 = g[e]; i1 = e; }
      int i2 = -1; float w2 = -1.f;
#pragma unroll
      for (int e = 0; e < 6; ++e) if (e != i1 && g[e] > w2) { w2 = g[e]; i2 = e; }
#pragma unroll
      for (int e = 0; e < 6; ++e)
        gates[(t0 + s) * 6 + e] = (e == i1) ? w1 : (e == i2) ? w2 : 0.f;
    }
  } else if (bid < 5120) {
    // ---- W_base^T -> Wcat[:, :2048] ----
    __shared__ bf16 tl[64][65];
    int b = bid - 4096;
    int bi = b >> 5, bj = b & 31;
    int k0 = bi * 64, n0 = bj * 64;
    int r = tid >> 2, c0 = (tid & 3) << 4;
#pragma unroll
    for (int q = 0; q < 4; ++q) {
      f32x4 v = *(const f32x4*)(W + (long)(k0 + r) * DDIM + n0 + c0 + q * 4);
#pragma unroll
      for (int j = 0; j < 4; ++j) tl[r][c0 + q * 4 + j] = __float2bfloat16(v[j]);
    }
    __syncthreads();
    __align__(16) bf16 o[16];
#pragma unroll
    for (int i = 0; i < 16; ++i) o[i] = tl[c0 + i][r];
    *(s16x8*)(Wcat + (long)(n0 + r) * KDIM + k0 + c0) = *(const s16x8*)o;
    *(s16x8*)(Wcat + (long)(n0 + r) * KDIM + k0 + c0 + 8) = *(const s16x8*)(o + 8);
  } else if (bid < 6144) {
    // ---- A_cat^T -> AcT ----
    int idx = (bid - 5120) * 256 + tid;            // over 128*2048
    int c = idx >> 11, d = idx & 2047;
    float v = 0.f;
    if (c < 16)       v = A_s[d * 16 + c];
    else if (c < 112) { int cr = c - 16; v = A_r[((long)(cr >> 4) * DDIM + d) * 16 + (cr & 15)]; }
    AcT[(long)c * DDIM + d] = __float2bfloat16(v);
  } else {
    // ---- B_cat^T -> Wcat[:, 2048:] ----
    int idx = (bid - 6144) * 256 + tid;            // over 2048*128
    int n = idx >> 7, c = idx & 127;
    float v = 0.f;
    if (c < 16)       v = Bs[c * DDIM + n];
    else if (c < 112) v = Br[(long)(c - 16) * DDIM + n];
    Wcat[(long)n * KDIM + 2048 + c] = __float2bfloat16(v);
  }
}

// ---------------- staging: [ROWS x 64] bf16 tile, LDS-linear (lora kernel) ----------------

template <int ROWS>
__device__ __forceinline__ void stage_tile(const bf16* __restrict__ g, long rs,
                                           bf16* lds, int wave, int lane) {
#pragma unroll
  for (int i = 0; i < (ROWS >> 5); ++i) {
    int chunk_base = (i * 4 + wave) * 64;
    int byte = (chunk_base + lane) * 16;
    int row = byte >> 7;
    int col = (byte & 127) >> 1;
    __builtin_amdgcn_global_load_lds(
        (const AS1 void*)(g + (long)row * rs + col),
        (AS3 void*)(lds + chunk_base * 8), 16, 0, 0);
  }
}

// ---------------- K2: lora, 32 tokens/block (round-16 proven, unchanged) ----------------

__global__ __launch_bounds__(256) void lora_kernel(
    bf16* __restrict__ xh, const bf16* __restrict__ AcT,
    const float* __restrict__ gates) {
  __shared__ __align__(16) short smem[2 * 160 * 64];   // 40 KB
  __shared__ float G[32][6];
  int tid = threadIdx.x, wave = tid >> 6, lane = tid & 63;
  int wm = wave >> 1, wn = wave & 1;
  long m0 = (long)blockIdx.x * 32;

  auto Xbuf = [&](int b) { return (bf16*)smem + b * 160 * 64; };
  auto Bbuf = [&](int b) { return (bf16*)smem + b * 160 * 64 + 32 * 64; };

  stage_tile<32>(xh + m0 * KDIM, KDIM, Xbuf(0), wave, lane);
  stage_tile<128>(AcT, DDIM, Bbuf(0), wave, lane);
  for (int i = tid; i < 192; i += 256) G[i / 6][i % 6] = gates[(m0 + i / 6) * 6 + i % 6];
  __syncthreads();

  f32x4 acc[4];
#pragma unroll
  for (int i = 0; i < 4; ++i) acc[i] = f32x4{0.f, 0.f, 0.f, 0.f};

  for (int kt = 0; kt < 32; ++kt) {
    int cur = kt & 1;
    if (kt < 31) {
      int k1 = (kt + 1) * 64;
      stage_tile<32>(xh + m0 * KDIM + k1, KDIM, Xbuf(cur ^ 1), wave, lane);
      stage_tile<128>(AcT + k1, DDIM, Bbuf(cur ^ 1), wave, lane);
    }
    if (kt > 0) {
      if (kt < 31) asm volatile("s_waitcnt vmcnt(5)" ::: "memory");
      else         asm volatile("s_waitcnt vmcnt(0)" ::: "memory");
      __builtin_amdgcn_sched_barrier(0);
      __builtin_amdgcn_s_barrier();
      __builtin_amdgcn_sched_barrier(0);
    }
    bf16* X_s = Xbuf(cur);
    bf16* B_s = Bbuf(cur);
#pragma unroll
    for (int kk = 0; kk < 2; ++kk) {
      bf16x8 a = *(const bf16x8*)(X_s + (wm * 16 + (lane & 15)) * 64 + kk * 32 + (lane >> 4) * 8);
#pragma unroll
      for (int nr = 0; nr < 4; ++nr) {
        bf16x8 b = *(const bf16x8*)(B_s + (wn * 64 + nr * 16 + (lane & 15)) * 64 + kk * 32 + (lane >> 4) * 8);
        acc[nr] = __builtin_amdgcn_mfma_f32_16x16x32_bf16(a, b, acc[nr], 0, 0, 0);
      }
    }
    __builtin_amdgcn_sched_barrier(0);
    __builtin_amdgcn_s_barrier();
  }

  bf16* H = (bf16*)smem;
#pragma unroll
  for (int nr = 0; nr < 4; ++nr) {
    int c = wn * 64 + nr * 16 + (lane & 15);
#pragma unroll
    for (int reg = 0; reg < 4; ++reg) {
      int tl = wm * 16 + 4 * (lane >> 4) + reg;
      float wgt = (c < 16) ? 1.f : (c < 112 ? G[tl][(c - 16) >> 4] : 0.f);
      H[tl * 128 + c] = __float2bfloat16(acc[nr][reg] * wgt);
    }
  }
  __syncthreads();
#pragma unroll
  for (int p = 0; p < 2; ++p) {
    int v = p * 256 + tid;
    int row = v >> 4, ch = (v & 15) * 8;
    *(s16x8*)(xh + (m0 + row) * KDIM + 2048 + ch) = *(const s16x8*)(H + row * 128 + ch);
  }
}

// ---------------- kernel B (round-16 v11 exact, frozen): 8-phase 256x256, vmcnt(6) q1/q3 ----------

__global__ __launch_bounds__(512, 2) void gemm256_kernel(
    const bf16* __restrict__ xh, const bf16* __restrict__ Wcat,
    const float* __restrict__ b_base, float* __restrict__ out) {
  extern __shared__ char sm[];
  int tid = threadIdx.x, wave = tid >> 6, lane = tid & 63;
  int wr = wave >> 2, wc = wave & 3;   // 2x4 wave grid; per-wave 128 x 64 output

  // XCD-bijective swizzle (nwg = 512, divisible by 8)
  int bid = blockIdx.x;
  int cpx = gridDim.x >> 3;
  int swz = (bid & 7) * cpx + (bid >> 3);
  long m0 = (long)(swz >> 3) * 256;    // 64 x 8 grid
  int n0 = (swz & 7) * 256;

  // proven-0-conflict frag constants: row = lane&15, slot = lane>>4, XOR ((lane>>1)&3)<<4
  int cp = ((lane >> 4) << 4) ^ (((lane >> 1) & 3) << 4);

  float bias[4];
#pragma unroll
  for (int nf = 0; nf < 4; ++nf) bias[nf] = b_base[n0 + wc * 64 + nf * 16 + (lane & 15)];

  f32x4 acc[8][4];
#pragma unroll
  for (int i = 0; i < 8; ++i)
#pragma unroll
    for (int j = 0; j < 4; ++j) acc[i][j] = f32x4{0.f, 0.f, 0.f, 0.f};

  const bf16* Agl = xh + m0 * KDIM;
  const bf16* Bgl = Wcat + (long)n0 * KDIM;

  // stage one 8KB subtile (op: 0=A,1=B; half h; ks s) of K-tile t: 1 load/thread
  auto stage_sub = [&](int t, int op, int h, int s) {
    int row = tid >> 2;
    int scol = ((((tid & 3) << 4) ^ (((row >> 1) & 3) << 4)) >> 1);
    const bf16* src = (op ? Bgl : Agl) + (long)(h * 128 + row) * KDIM + t * 64 + s * 32 + scol;
    char* dst = sm + (t & 1) * 65536 + op * 32768 + (h * 2 + s) * 8192 + tid * 16;
    __builtin_amdgcn_global_load_lds((const AS1 void*)src, (AS3 void*)dst, 16, 0, 0);
  };

  bf16x8 a[4], b[4];

  // phase: quadrant (ks, mh); optional stage of 2 subtiles; counted vmcnt; optional barrier
  auto phase = [&](int buf, int ks, int mh, bool doStage, int stT, int stOp, int stKs,
                   int vm, bool bar) {
    if (mh == 0) {
      char* Bb = sm + buf * 65536 + 32768 + ((wc >> 1) * 2 + ks) * 8192;
#pragma unroll
      for (int n = 0; n < 4; ++n)
        b[n] = *(const bf16x8*)(Bb + ((wc & 1) * 64 + n * 16 + (lane & 15)) * 64 + cp);
    }
    char* Ab = sm + buf * 65536 + (wr * 2 + ks) * 8192;
#pragma unroll
    for (int j = 0; j < 4; ++j)
      a[j] = *(const bf16x8*)(Ab + ((mh * 4 + j) * 16 + (lane & 15)) * 64 + cp);
    if (doStage) { stage_sub(stT, stOp, 0, stKs); stage_sub(stT, stOp, 1, stKs); }
    __builtin_amdgcn_s_setprio(1);
#pragma unroll
    for (int j = 0; j < 4; ++j)
#pragma unroll
      for (int n = 0; n < 4; ++n)
        acc[mh * 4 + j][n] = __builtin_amdgcn_mfma_f32_16x16x32_bf16(a[j], b[n], acc[mh * 4 + j][n], 0, 0, 0);
    __builtin_amdgcn_s_setprio(0);
    if (vm == 6)      asm volatile("s_waitcnt vmcnt(6)" ::: "memory");
    else if (vm == 0) asm volatile("s_waitcnt vmcnt(0)" ::: "memory");
    if (bar) __builtin_amdgcn_s_barrier();
  };

  // prologue: stage t0 ks0+ks1, t1 ks0 (12 loads/thread); t0 resident after vmcnt(8)+barrier
  stage_sub(0, 0, 0, 0); stage_sub(0, 0, 1, 0); stage_sub(0, 1, 0, 0); stage_sub(0, 1, 1, 0);
  stage_sub(0, 0, 0, 1); stage_sub(0, 0, 1, 1); stage_sub(0, 1, 0, 1); stage_sub(0, 1, 1, 1);
  stage_sub(1, 0, 0, 0); stage_sub(1, 0, 1, 0); stage_sub(1, 1, 0, 0); stage_sub(1, 1, 1, 0);
  asm volatile("s_waitcnt vmcnt(8)" ::: "memory");
  __builtin_amdgcn_s_barrier();

  // main loop: K-tiles 0..31; vmcnt(6)+barrier at q1 and q3 ONLY
  for (int i = 0; i < 16; ++i) {
    int t0 = 2 * i;
    phase(0, 0, 0, true, t0 + 1, 0, 1, -1, false);
    phase(0, 0, 1, true, t0 + 1, 1, 1, 6, true);
    phase(0, 1, 0, true, t0 + 2, 0, 0, -1, false);
    phase(0, 1, 1, true, t0 + 2, 1, 0, 6, true);
    phase(1, 0, 0, true, t0 + 2, 0, 1, -1, false);
    phase(1, 0, 1, true, t0 + 2, 1, 1, 6, true);
    phase(1, 1, 0, true, t0 + 3, 0, 0, -1, false);
    phase(1, 1, 1, true, t0 + 3, 1, 0, 6, true);
  }
  // tail: tile 32 stages 33-ks1 at q0/q1; q1 vm6+bar, q3 vm0+bar; tile 33 free-run
  phase(0, 0, 0, true, 33, 0, 1, -1, false);
  phase(0, 0, 1, true, 33, 1, 1, 6, true);
  phase(0, 1, 0, false, 0, 0, 0, -1, false);
  phase(0, 1, 1, false, 0, 0, 0, 0, true);
  phase(1, 0, 0, false, 0, 0, 0, -1, false);
  phase(1, 0, 1, false, 0, 0, 0, -1, false);
  phase(1, 1, 0, false, 0, 0, 0, -1, false);
  phase(1, 1, 1, false, 0, 0, 0, -1, false);

  // epilogue: bias add, fp32 LDS repack in 2 passes, XOR key (r>>2)&3 << 6,
  // 1024B-coalesced float4 stores
  float* Cs = (float*)sm;
#pragma unroll
  for (int p = 0; p < 2; ++p) {
    __syncthreads();
#pragma unroll
    for (int q = 0; q < 4; ++q) {
#pragma unroll
      for (int nf = 0; nf < 4; ++nf) {
#pragma unroll
        for (int reg = 0; reg < 4; ++reg) {
          int r = wr * 64 + q * 16 + 4 * (lane >> 4) + reg;
          int colb = ((wc * 64 + nf * 16 + (lane & 15)) * 4) ^ (((r >> 2) & 3) << 6);
          *(float*)((char*)Cs + r * 1024 + colb) = acc[p * 4 + q][nf][reg] + bias[nf];
        }
      }
    }
    __syncthreads();
#pragma unroll 4
    for (int it = 0; it < 16; ++it) {
      int v = it * 512 + tid;
      int r = v >> 6, slot = v & 63;
      f32x4 val = *(const f32x4*)((char*)Cs + r * 1024 + ((slot << 4) ^ (((r >> 2) & 3) << 6)));
      long grow = m0 + (r >> 6) * 128 + p * 64 + (r & 63);
      *(f32x4*)(out + grow * DDIM + n0 + slot * 4) = val;
    }
  }
}

// ---------------- launcher ----------------

extern "C" void kernel_launch(void* const* d_in, const int* in_sizes, int n_in,
                              void* d_out, int out_size, void* d_ws, size_t ws_size,
                              hipStream_t stream) {
  const float* x        = (const float*)d_in[0];
  const float* W_base   = (const float*)d_in[1];
  const float* b_base   = (const float*)d_in[2];
  const float* A_s      = (const float*)d_in[3];
  const float* B_s      = (const float*)d_in[4];
  const float* A_r      = (const float*)d_in[5];
  const float* B_r      = (const float*)d_in[6];
  const float* W_router = (const float*)d_in[7];
  const float* b_router = (const float*)d_in[8];
  float* out = (float*)d_out;

  char* ws = (char*)d_ws;
  bf16*  xh    = (bf16*)(ws);                    // 16384*2176*2 = 71,303,168 B
  bf16*  Wcat  = (bf16*)(ws + 71303168);         //  2048*2176*2 =  8,912,896 B
  bf16*  AcT   = (bf16*)(ws + 80216064);         //   128*2048*2 =    524,288 B
  float* gates = (float*)(ws + 80740352);        //   16384*6*4  =    393,216 B
  float* WrT   = (float*)(ws + 81133568);        //    6*2048*4  =     49,152 B

  (void)hipFuncSetAttribute((const void*)gemm256_kernel,
                            hipFuncAttributeMaxDynamicSharedMemorySize, 131072);

  wrt_kernel<<<48, 256, 0, stream>>>(W_router, WrT);
  conv_prep_kernel<<<7168, 256, 0, stream>>>(x, WrT, b_router, xh, gates,
                                             W_base, A_s, A_r, B_s, B_r, Wcat, AcT);
  lora_kernel<<<512, 256, 0, stream>>>(xh, AcT, gates);
  gemm256_kernel<<<512, 512, 131072, stream>>>(xh, Wcat, b_base, out);
}